// Round 9
// baseline (734.097 us; speedup 1.0000x reference)
//
#include <hip/hip_runtime.h>
#include <hip/hip_bf16.h>
#include <math.h>

#define NEGV -1000000000.0f

static constexpr int B_ = 16, N_ = 128, BN_ = 2048;
static constexpr int E_ = 384, V_ = 8000;

typedef __attribute__((ext_vector_type(8))) short short8v;
typedef __attribute__((ext_vector_type(4))) float f32x4;

// ---------------- helpers ----------------
__device__ inline float wave_sum(float v) {
#pragma unroll
  for (int o = 32; o; o >>= 1) v += __shfl_xor(v, o);
  return v;
}
__device__ inline float wave_max(float v) {
#pragma unroll
  for (int o = 32; o; o >>= 1) v = fmaxf(v, __shfl_xor(v, o));
  return v;
}
__device__ inline float fast_tanh(float x) {
  return 1.f - 2.f / (1.f + __expf(2.f * x));
}
__device__ inline float fast_tanh_pre(float x2) {  // input pre-scaled by 2
  return 1.f - 2.f / (1.f + __expf(x2));
}
__device__ inline float fast_sig(float x) {
  return 1.f / (1.f + __expf(-x));
}
__device__ __forceinline__ void gl16(const void* g, void* l) {
  __builtin_amdgcn_global_load_lds((const __attribute__((address_space(1))) void*)g,
                                   (__attribute__((address_space(3))) void*)l, 16, 0, 0);
}

// ---------------- embedding gather -> bf16 ----------------
__global__ __launch_bounds__(256) void embed_kernel(
    const int* __restrict__ ids, const float* __restrict__ emb,
    __hip_bfloat16* __restrict__ xb) {
  const int row = blockIdx.x;
  const int id = ids[row];
  for (int e = threadIdx.x; e < E_; e += 256)
    xb[(size_t)row * E_ + e] = __float2bfloat16(emb[(size_t)id * E_ + e]);
}

// ---------------- multi-segment fp32 -> bf16 cast ----------------
struct CastArgs {
  const float* s[12];
  unsigned long long d[12];
  int base[12];
  int total;
  int special;  // segment index with ptr_W [128][513]->[128][512] packing, or -1
};
__device__ inline void cast_body(const CastArgs& a, int gsize, int gid0) {
  const int nq = a.total >> 2;
  for (int q = gid0; q < nq; q += gsize) {
    const int e = q << 2;
    int k = 11;
    while (e < a.base[k]) --k;
    const int i = e - a.base[k];
    __hip_bfloat16* dst = (__hip_bfloat16*)a.d[k] + i;
    if (k == a.special) {
      const int row = i >> 9, col = i & 511;
      const float* sp = a.s[k] + (size_t)row * 513 + col;
#pragma unroll
      for (int u = 0; u < 4; ++u) dst[u] = __float2bfloat16(sp[u]);
    } else {
      float4 v = *(const float4*)(a.s[k] + i);
      __hip_bfloat16 h0 = __float2bfloat16(v.x), h1 = __float2bfloat16(v.y);
      __hip_bfloat16 h2 = __float2bfloat16(v.z), h3 = __float2bfloat16(v.w);
      ushort4 u4 = {*(unsigned short*)&h0, *(unsigned short*)&h1,
                    *(unsigned short*)&h2, *(unsigned short*)&h3};
      *(ushort4*)dst = u4;
    }
  }
}
__global__ __launch_bounds__(256) void cast_kernel(CastArgs a) {
  cast_body(a, gridDim.x * 256, blockIdx.x * 256 + threadIdx.x);
}

// ---------------- 128x128-tile bf16 MFMA GEMM (big GEMMs) ----------------
template <int ACT, bool MASK>
__global__ __launch_bounds__(256) void bgemm_kernel(
    const __hip_bfloat16* __restrict__ A, int lda,
    const __hip_bfloat16* __restrict__ W, int ldw,
    const float* __restrict__ bias,
    float* __restrict__ C, int ldc,
    __hip_bfloat16* __restrict__ Cb, int ldcb,
    int M, int N, int K,
    const int* __restrict__ mask, int ldm) {
  __shared__ __hip_bfloat16 Al[2][4096];
  __shared__ __hip_bfloat16 Bl[2][4096];
  const int tid = threadIdx.x;
  const int wid = tid >> 6, lane = tid & 63;
  const int m0 = blockIdx.y * 128, n0 = blockIdx.x * 128;
  const int nkt = K >> 5;
  const int rm = (wid >> 1) << 6, rn = (wid & 1) << 6;
  const int lrow = lane & 15, kq = lane >> 4;
  const int fs = ((lrow >> 1) & 3) << 4;

  f32x4 acc[4][4];
#pragma unroll
  for (int i = 0; i < 4; ++i)
#pragma unroll
    for (int j = 0; j < 4; ++j) acc[i][j] = {0.f, 0.f, 0.f, 0.f};

  auto stage = [&](int bi, int kt) {
#pragma unroll
    for (int c = 0; c < 2; ++c) {
      const int p = ((c * 4 + wid) << 6) + lane;
      const int row = p >> 2, cb = (p & 3) << 4;
      const int sw = ((row >> 1) & 3) << 4;
      const unsigned loff = (unsigned)__builtin_amdgcn_readfirstlane((c * 4 + wid) << 10);
      {
        const char* src = (const char*)A + ((size_t)(m0 + row) * lda + (size_t)kt * 32) * 2 + (cb ^ sw);
        gl16(src, (char*)&Al[bi][0] + loff);
      }
      {
        int gr = n0 + row;
        if (gr >= N) gr = N - 1;
        const char* src = (const char*)W + ((size_t)gr * ldw + (size_t)kt * 32) * 2 + (cb ^ sw);
        gl16(src, (char*)&Bl[bi][0] + loff);
      }
    }
  };
  auto compute = [&](int bi) {
    const char* Ab = (const char*)&Al[bi][0];
    const char* Bb = (const char*)&Bl[bi][0];
    const int roff = (kq << 4) ^ fs;
    short8v a[4], b[4];
#pragma unroll
    for (int i = 0; i < 4; ++i)
      a[i] = *(const short8v*)(Ab + (rm + i * 16 + lrow) * 64 + roff);
#pragma unroll
    for (int j = 0; j < 4; ++j)
      b[j] = *(const short8v*)(Bb + (rn + j * 16 + lrow) * 64 + roff);
#pragma unroll
    for (int i = 0; i < 4; ++i)
#pragma unroll
      for (int j = 0; j < 4; ++j)
        acc[i][j] = __builtin_amdgcn_mfma_f32_16x16x32_bf16(a[i], b[j], acc[i][j], 0, 0, 0);
  };

  stage(0, 0);
  for (int kt = 0; kt < nkt; ++kt) {
    __syncthreads();
    if (kt + 1 < nkt) stage((kt + 1) & 1, kt + 1);
    compute(kt & 1);
  }

#pragma unroll
  for (int i = 0; i < 4; ++i) {
#pragma unroll
    for (int r = 0; r < 4; ++r) {
      const int m = m0 + rm + i * 16 + kq * 4 + r;
#pragma unroll
      for (int j = 0; j < 4; ++j) {
        const int n = n0 + rn + j * 16 + lrow;
        if (n < N) {
          float v = acc[i][j][r] + (bias ? bias[n] : 0.f);
          if (ACT == 1) v = fast_tanh(v);
          if (MASK) {
            if (mask[(size_t)m * ldm + n] == 0) v = NEGV;
          }
          if (C) C[(size_t)m * ldc + n] = v;
          if (Cb) Cb[(size_t)m * ldcb + n] = __float2bfloat16(v);
        }
      }
    }
  }
}

// ---------------- 64x64-tile bf16 MFMA GEMM ----------------
// ACT: 0 none, 1 tanh(v+bias), 2 v*=2 (prescale for score)
// TROUT: 0 normal, 1 etT transposed-out, 2 split wg(tanh,f32)/base(raw,f32)
template <int ACT, int TROUT>
__global__ __launch_bounds__(256) void bgemm64_kernel(
    const __hip_bfloat16* __restrict__ A, int lda,
    const __hip_bfloat16* __restrict__ W, int ldw,
    const float* __restrict__ bias, const float* __restrict__ bias2,
    float* __restrict__ C, int ldc, float* __restrict__ C2,
    __hip_bfloat16* __restrict__ Cb, int ldcb,
    int M, int N, int K,
    long aBs, long wBs, long cBs) {
  __shared__ __hip_bfloat16 Al[2][2048];
  __shared__ __hip_bfloat16 Bl[2][2048];
  A += (size_t)blockIdx.z * aBs;
  W += (size_t)blockIdx.z * wBs;
  const int tid = threadIdx.x;
  const int wid = tid >> 6, lane = tid & 63;
  const int m0 = blockIdx.y * 64, n0 = blockIdx.x * 64;
  const int nkt = K >> 5;
  const int rm = (wid >> 1) << 5, rn = (wid & 1) << 5;
  const int lrow = lane & 15, kq = lane >> 4;
  const int fs = ((lrow >> 1) & 3) << 4;

  f32x4 acc[2][2];
#pragma unroll
  for (int i = 0; i < 2; ++i)
#pragma unroll
    for (int j = 0; j < 2; ++j) acc[i][j] = {0.f, 0.f, 0.f, 0.f};

  auto stage = [&](int bi, int kt) {
    const int p = tid;
    const int row = p >> 2, cb = (p & 3) << 4;
    const int sw = ((row >> 1) & 3) << 4;
    const unsigned loff = (unsigned)__builtin_amdgcn_readfirstlane(wid << 10);
    {
      const char* src = (const char*)A + ((size_t)(m0 + row) * lda + (size_t)kt * 32) * 2 + (cb ^ sw);
      gl16(src, (char*)&Al[bi][0] + loff);
    }
    {
      const char* src = (const char*)W + ((size_t)(n0 + row) * ldw + (size_t)kt * 32) * 2 + (cb ^ sw);
      gl16(src, (char*)&Bl[bi][0] + loff);
    }
  };
  auto compute = [&](int bi) {
    const char* Ab = (const char*)&Al[bi][0];
    const char* Bb = (const char*)&Bl[bi][0];
    const int roff = (kq << 4) ^ fs;
    short8v a[2], b[2];
#pragma unroll
    for (int i = 0; i < 2; ++i)
      a[i] = *(const short8v*)(Ab + (rm + i * 16 + lrow) * 64 + roff);
#pragma unroll
    for (int j = 0; j < 2; ++j)
      b[j] = *(const short8v*)(Bb + (rn + j * 16 + lrow) * 64 + roff);
#pragma unroll
    for (int i = 0; i < 2; ++i)
#pragma unroll
      for (int j = 0; j < 2; ++j)
        acc[i][j] = __builtin_amdgcn_mfma_f32_16x16x32_bf16(a[i], b[j], acc[i][j], 0, 0, 0);
  };

  stage(0, 0);
  for (int kt = 0; kt < nkt; ++kt) {
    __syncthreads();
    if (kt + 1 < nkt) stage((kt + 1) & 1, kt + 1);
    compute(kt & 1);
  }

#pragma unroll
  for (int i = 0; i < 2; ++i) {
#pragma unroll
    for (int r = 0; r < 4; ++r) {
      const int m = m0 + rm + i * 16 + kq * 4 + r;
#pragma unroll
      for (int j = 0; j < 2; ++j) {
        const int n = n0 + rn + j * 16 + lrow;
        float v = acc[i][j][r];
        if (TROUT == 2) {
          if (n < 512) {
            C[(size_t)m * ldc + n] = fast_tanh(v + bias[n]);
          } else {
            C2[(size_t)m * 128 + (n - 512)] = v + bias2[n - 512];
          }
        } else {
          if (ACT == 2) v *= 2.f;
          else {
            v += (bias ? bias[n] : 0.f);
            if (ACT == 1) v = fast_tanh(v);
          }
          if (TROUT == 1) {
            Cb[(((size_t)(m >> 7) * 512 + n) << 7) + (m & 127)] = __float2bfloat16(v);
          } else {
            if (C) C[(size_t)m * ldc + n] = v;
            if (Cb) Cb[(size_t)m * ldcb + n + (size_t)blockIdx.z * cBs] = __float2bfloat16(v);
          }
        }
      }
    }
  }
}

// ---------------- FUSED: lstm (96) + scatter (384) + cast2 (64) ----------------
// lstm: two-phase poll (ushort sentinel probe -> 64B line fetch); 512B publish
// via ONE exec-masked wave-wide store instruction (sector-atomic), rotated
// across waves so the store-ack penalty hits each wave 1-in-4 steps; own-block
// region copied LDS->LDS. Weights staged directly from f32.
// scatter: progressive, polls hbuf ushorts (s-ascending), reconstructs
// ehsb/ehsT/catb. cast2: plain weight casts. All roles fully resident.
__global__ __launch_bounds__(256) void fused_kernel(
    const __hip_bfloat16* __restrict__ xp16,   // [3][2048][2048]
    const float* __restrict__ whhF, const float* __restrict__ whhB,
    const float* __restrict__ whhD,
    __hip_bfloat16* __restrict__ hbuf,         // [3][128][32][16b][16d]
    __hip_bfloat16* __restrict__ ehsb, __hip_bfloat16* __restrict__ ehsT,
    __hip_bfloat16* __restrict__ catb,
    CastArgs ca2) {
  extern __shared__ char sm[];
  const int bid = blockIdx.x;
  const int tid = threadIdx.x;

  if (bid >= 480) {  // ---- cast2 role ----
    cast_body(ca2, 64 * 256, (bid - 480) * 256 + tid);
    return;
  }

  if (bid >= 96) {  // ---- scatter role ----
    const int sb = bid - 96;
    const int l = sb >> 7, b = (sb >> 3) & 15, dgrp = sb & 7;
    unsigned short (*tile)[130] = (unsigned short(*)[130])sm;
    const int t4 = tid >> 6, dl = tid & 63;
    const bool rev = (l == 1);
    const char* hb = (const char*)(hbuf + (size_t)l * 128 * 8192);
    const unsigned lineoff = (unsigned)((dgrp * 4 + (dl >> 4)) * 512 + b * 32 + (dl & 15) * 2);
    for (int u = 0; u < 8; ++u) {
      const int sbase = t4 * 4 + u * 16;  // ascending s = arrival order
      unsigned o0 = (unsigned)(sbase * 16384) + lineoff;
      unsigned h0, h1, h2, h3;
      while (true) {
        asm volatile(
            "global_load_ushort %0, %4, %8 sc0 sc1\n\t"
            "global_load_ushort %1, %5, %8 sc0 sc1\n\t"
            "global_load_ushort %2, %6, %8 sc0 sc1\n\t"
            "global_load_ushort %3, %7, %8 sc0 sc1\n\t"
            "s_waitcnt vmcnt(0)"
            : "=&v"(h0), "=&v"(h1), "=&v"(h2), "=&v"(h3)
            : "v"(o0), "v"(o0 + 16384u), "v"(o0 + 32768u), "v"(o0 + 49152u),
              "s"(hb)
            : "memory");
        if (((h0 & 0xffffu) != 0x7f7fu) & ((h1 & 0xffffu) != 0x7f7fu) &
            ((h2 & 0xffffu) != 0x7f7fu) & ((h3 & 0xffffu) != 0x7f7fu)) break;
        __builtin_amdgcn_s_sleep(8);
      }
      const unsigned hv[4] = {h0, h1, h2, h3};
#pragma unroll
      for (int w = 0; w < 4; ++w) {
        const int s = sbase + w;
        const int t = rev ? 127 - s : s;
        tile[dl][t] = (unsigned short)hv[w];
      }
    }
    __syncthreads();
    if (l < 2) {
      const int r = tid >> 2, seg = tid & 3;
      ushort4* dstT = (ushort4*)(ehsT + ((size_t)b * 1024 + l * 512 + dgrp * 64 + r) * 128 + seg * 32);
      const unsigned short* srcT = &tile[r][seg * 32];
#pragma unroll
      for (int q = 0; q < 8; ++q) dstT[q] = *(const ushort4*)(srcT + q * 4);
      const int t2 = tid >> 1, half = tid & 1;
      unsigned short buf[32];
#pragma unroll
      for (int q = 0; q < 32; ++q) buf[q] = tile[half * 32 + q][t2];
      ushort4* dstB = (ushort4*)(ehsb + ((size_t)(b * 128 + t2)) * 1024 + l * 512 + dgrp * 64 + half * 32);
#pragma unroll
      for (int q = 0; q < 8; ++q) dstB[q] = *(const ushort4*)(buf + q * 4);
    } else {
      const int t2 = tid >> 1, half = tid & 1;
      unsigned short buf[32];
#pragma unroll
      for (int q = 0; q < 32; ++q) buf[q] = tile[half * 32 + q][t2];
      ushort4* dstB = (ushort4*)(catb + ((size_t)(b * 128 + t2)) * 1536 + dgrp * 64 + half * 32);
#pragma unroll
      for (int q = 0; q < 8; ++q) dstB[q] = *(const ushort4*)(buf + q * 4);
    }
    return;
  }

  // ---- LSTM role ----
  const int l = bid >> 5, g = bid & 31;
  const int lane = tid & 63, wid = tid >> 6;
  char* smW = sm;                                   // 65536
  char* smH = sm + 65536;                           // 16384
  __hip_bfloat16* hout = (__hip_bfloat16*)(sm + 65536 + 16384);  // 512

  // stage weights from f32, reordered dim-major: LDS row lr = d_local*4 + gate
  const float* wsrc = (l == 0) ? whhF : ((l == 1) ? whhB : whhD);
  auto cv = [](float x) -> unsigned {
    __hip_bfloat16 h = __float2bfloat16(x);
    return (unsigned)*(unsigned short*)&h;
  };
  for (int p = tid; p < 4096; p += 256) {
    const int r = p >> 6, cb = (p & 63) << 4;
    const int grow = (r & 3) * 512 + (g << 4) + (r >> 2);
    const float* srcp = wsrc + (size_t)grow * 512 + ((p & 63) << 3);
    float4 u0 = *(const float4*)srcp;
    float4 u1 = *(const float4*)(srcp + 4);
    uint4 q;
    q.x = cv(u0.x) | (cv(u0.y) << 16);
    q.y = cv(u0.z) | (cv(u0.w) << 16);
    q.z = cv(u1.x) | (cv(u1.y) << 16);
    q.w = cv(u1.z) | (cv(u1.w) << 16);
    *(uint4*)(smW + r * 1024 + (cb ^ ((r & 7) << 4))) = q;
  }

  const int lrow = lane & 15, kq = lane >> 4;
  const int swz = (lrow & 7) << 4;
  const char* aB = smW + (wid * 16 + lrow) * 1024;
  const char* bB = smH + lrow * 1024;
  const int dl16 = wid * 4 + kq;
  const int dg = (g << 4) + dl16;
  const int bb = lrow;
  const bool rev = (l == 1);
  const __hip_bfloat16* xl = xp16 + (size_t)l * 2048 * 2048;
  __hip_bfloat16* hb_l = hbuf + (size_t)l * 128 * 8192;
  const int gq = tid >> 3;
  const int b0 = (tid & 7) * 2;
  const int gb = gq * 32;
  const int sw0 = (b0 & 7) << 4, sw1 = ((b0 + 1) & 7) << 4;
  float c = 0.f;

  for (int s = 0; s < 128; ++s) {
    const int t = rev ? 127 - s : s;
    const size_t xro = (size_t)(bb * 128 + t) * 2048 + dg;
    const float xgi = __bfloat162float(xl[xro]);
    const float xgf = __bfloat162float(xl[xro + 512]);
    const float xgg = __bfloat162float(xl[xro + 1024]);
    const float xgo = __bfloat162float(xl[xro + 1536]);

    if (s > 0) {
      if (gq != g) {
        const char* hsrc = (const char*)(hb_l + (size_t)(s - 1) * 8192);
        const unsigned loff = (unsigned)(tid * 64);
        unsigned hv;
        while (true) {
          asm volatile(
              "global_load_ushort %0, %1, %2 sc0 sc1\n\t"
              "s_waitcnt vmcnt(0)"
              : "=&v"(hv) : "v"(loff), "s"(hsrc) : "memory");
          if ((hv & 0xffffu) != 0x7f7fu) break;
          __builtin_amdgcn_s_sleep(1);
        }
        f32x4 q0, q1, q2, q3;
        asm volatile(
            "global_load_dwordx4 %0, %4, %5 sc0 sc1\n\t"
            "global_load_dwordx4 %1, %4, %5 offset:16 sc0 sc1\n\t"
            "global_load_dwordx4 %2, %4, %5 offset:32 sc0 sc1\n\t"
            "global_load_dwordx4 %3, %4, %5 offset:48 sc0 sc1\n\t"
            "s_waitcnt vmcnt(0)"
            : "=&v"(q0), "=&v"(q1), "=&v"(q2), "=&v"(q3)
            : "v"(loff), "s"(hsrc) : "memory");
        *(f32x4*)(smH + b0 * 1024 + (gb ^ sw0)) = q0;
        *(f32x4*)(smH + b0 * 1024 + ((gb + 16) ^ sw0)) = q1;
        *(f32x4*)(smH + (b0 + 1) * 1024 + (gb ^ sw1)) = q2;
        *(f32x4*)(smH + (b0 + 1) * 1024 + ((gb + 16) ^ sw1)) = q3;
      } else {
        // own region: copy prev-step h from hout (LDS), no global RT
        const char* hl = (const char*)hout + b0 * 32;
        f32x4 c0 = *(const f32x4*)(hl);
        f32x4 c1 = *(const f32x4*)(hl + 16);
        f32x4 c2 = *(const f32x4*)(hl + 32);
        f32x4 c3 = *(const f32x4*)(hl + 48);
        *(f32x4*)(smH + b0 * 1024 + (gb ^ sw0)) = c0;
        *(f32x4*)(smH + b0 * 1024 + ((gb + 16) ^ sw0)) = c1;
        *(f32x4*)(smH + (b0 + 1) * 1024 + (gb ^ sw1)) = c2;
        *(f32x4*)(smH + (b0 + 1) * 1024 + ((gb + 16) ^ sw1)) = c3;
      }
    } else {
      const f32x4 z = {0.f, 0.f, 0.f, 0.f};
      *(f32x4*)(smH + b0 * 1024 + (gb ^ sw0)) = z;
      *(f32x4*)(smH + b0 * 1024 + ((gb + 16) ^ sw0)) = z;
      *(f32x4*)(smH + (b0 + 1) * 1024 + (gb ^ sw1)) = z;
      *(f32x4*)(smH + (b0 + 1) * 1024 + ((gb + 16) ^ sw1)) = z;
    }
    __syncthreads();  // A: smH fully staged

    f32x4 acc0 = {0.f, 0.f, 0.f, 0.f}, acc1 = {0.f, 0.f, 0.f, 0.f};
#pragma unroll
    for (int kt = 0; kt < 16; kt += 2) {
      const int off0 = ((kt * 64 + (kq << 4)) ^ swz);
      const int off1 = (((kt + 1) * 64 + (kq << 4)) ^ swz);
      short8v a0 = *(const short8v*)(aB + off0);
      short8v b0v = *(const short8v*)(bB + off0);
      short8v a1 = *(const short8v*)(aB + off1);
      short8v b1v = *(const short8v*)(bB + off1);
      acc0 = __builtin_amdgcn_mfma_f32_16x16x32_bf16(a0, b0v, acc0, 0, 0, 0);
      acc1 = __builtin_amdgcn_mfma_f32_16x16x32_bf16(a1, b1v, acc1, 0, 0, 0);
    }
    const f32x4 acc = acc0 + acc1;  // acc[r] = gate r for (dg, bb)

    const float gi = acc[0] + xgi;
    const float gf = acc[1] + xgf;
    const float gg = acc[2] + xgg;
    const float go = acc[3] + xgo;
    c = fmaf(fast_sig(gf), c, fast_sig(gi) * fast_tanh(gg));
    const float h = fast_sig(go) * fast_tanh(c);
    __hip_bfloat16 hb16 = __float2bfloat16(h);
    hout[bb * 16 + dl16] = hb16;
    __syncthreads();  // B: all MFMA reads of smH done + hout complete

    // publish: ONE wave-wide store instruction (sector-atomic), wave rotates
    if (wid == (s & 3) && (lane < 32)) {
      f32x4 hv4 = *(const f32x4*)((const char*)hout + lane * 16);
      char* hdst = (char*)(hb_l + (size_t)s * 8192);
      asm volatile("global_store_dwordx4 %0, %1, %2 sc0 sc1"
                   :: "v"((unsigned)((g << 9) + lane * 16)), "v"(hv4), "s"(hdst)
                   : "memory");
    }
    // no drain: ack folds into that wave's next poll vmcnt (1-in-4 steps)
  }
}

// ---------------- score + softmax -> alpha; 4 t's per block ----------------
// dterm/etT are pre-scaled by 2: tanh(d+e) = 1 - 2/(1+exp(d'+e'))
__global__ __launch_bounds__(256) void score_kernel(
    const float* __restrict__ dterm, const __hip_bfloat16* __restrict__ etT,
    const float* __restrict__ v_att, const int* __restrict__ src_mask,
    __hip_bfloat16* __restrict__ alphab) {
  const int b = blockIdx.x >> 5, tg = blockIdx.x & 31;
  const int t0 = tg * 4;
  const int tid = threadIdx.x;
  __shared__ float dt[4][512], vs[512], red[4][4][128], al[4][128];
  for (int i = tid; i < 2048; i += 256)
    dt[i >> 9][i & 511] = dterm[((size_t)(b * 128 + t0 + (i >> 9))) * 512 + (i & 511)];
  vs[tid] = v_att[tid];
  vs[tid + 256] = v_att[256 + tid];
  __syncthreads();
  const int n0 = (tid & 63) << 1, ah = tid >> 6;
  {
    const __hip_bfloat16* ep = etT + (((size_t)b * 512 + ah * 128) << 7) + n0;
    const float* vp = vs + ah * 128;
    const float* dp0 = &dt[0][ah * 128];
    const float* dp1 = &dt[1][ah * 128];
    const float* dp2 = &dt[2][ah * 128];
    const float* dp3 = &dt[3][ah * 128];
    float p00 = 0, p01 = 0, p10 = 0, p11 = 0, p20 = 0, p21 = 0, p30 = 0, p31 = 0;
    for (int a = 0; a < 128; ++a) {
      const unsigned u = *(const unsigned*)(ep + ((size_t)a << 7));
      unsigned u0 = u << 16, u1 = u & 0xffff0000u;
      const float e0 = __builtin_bit_cast(float, u0);
      const float e1 = __builtin_bit_cast(float, u1);
      const float va = vp[a];
      p00 = fmaf(va, fast_tanh_pre(dp0[a] + e0), p00);
      p01 = fmaf(va, fast_tanh_pre(dp0[a] + e1), p01);
      p10 = fmaf(va, fast_tanh_pre(dp1[a] + e0), p10);
      p11 = fmaf(va, fast_tanh_pre(dp1[a] + e1), p11);
      p20 = fmaf(va, fast_tanh_pre(dp2[a] + e0), p20);
      p21 = fmaf(va, fast_tanh_pre(dp2[a] + e1), p21);
      p30 = fmaf(va, fast_tanh_pre(dp3[a] + e0), p30);
      p31 = fmaf(va, fast_tanh_pre(dp3[a] + e1), p31);
    }
    red[0][ah][n0] = p00; red[0][ah][n0 + 1] = p01;
    red[1][ah][n0] = p10; red[1][ah][n0 + 1] = p11;
    red[2][ah][n0] = p20; red[2][ah][n0 + 1] = p21;
    red[3][ah][n0] = p30; red[3][ah][n0 + 1] = p31;
  }
  __syncthreads();
#pragma unroll
  for (int tp = 0; tp < 2; ++tp) {
    const int tt = tp * 2 + (tid >> 7);
    const int n = tid & 127;
    float sc = red[tt][0][n] + red[tt][1][n] + red[tt][2][n] + red[tt][3][n];
    if (src_mask[b * 128 + n] == 0) sc = NEGV;
    al[tt][n] = sc;
  }
  __syncthreads();
  {
    const int tt = tid >> 6, lane = tid & 63;
    const float v0 = al[tt][lane], v1 = al[tt][lane + 64];
    const float m = wave_max(fmaxf(v0, v1));
    const float e0 = __expf(v0 - m), e1 = __expf(v1 - m);
    const float inv = 1.f / wave_sum(e0 + e1);
    __hip_bfloat16* ap = alphab + ((size_t)(b * 128 + t0 + tt)) * 128;
    ap[lane] = __float2bfloat16(e0 * inv);
    ap[lane + 64] = __float2bfloat16(e1 * inv);
  }
}

// ---------------- pointer head assembly ----------------
__global__ __launch_bounds__(256) void pointer_kernel(
    const float* __restrict__ base, const float* __restrict__ wgout,
    const float* __restrict__ ptr_W, const float* __restrict__ ps_W,
    const float* __restrict__ ps_b, const int* __restrict__ src_mask,
    float* __restrict__ out0) {
  const int bt = blockIdx.x;
  const int b = bt >> 7, t = bt & 127;
  const int tid = threadIdx.x;
  __shared__ float r0[4], r1[4], r2[4], fin[3];
  float off_p = 0.f, diag_p = 0.f, sent_p;
  if (tid < 128) {
    const float ba = base[(size_t)bt * 128 + tid];
    const float pw = ps_W[tid];
    off_p = tanhf(ba) * pw;
    diag_p = tanhf(ba + ptr_W[tid * 513 + 512]) * pw;
  }
  sent_p = wgout[(size_t)bt * 512 + tid] + wgout[(size_t)bt * 512 + 256 + tid];
  off_p = wave_sum(off_p);
  diag_p = wave_sum(diag_p);
  sent_p = wave_sum(sent_p);
  const int wid = tid >> 6, lane = tid & 63;
  if (lane == 0) { r0[wid] = off_p; r1[wid] = diag_p; r2[wid] = sent_p; }
  __syncthreads();
  if (tid == 0) {
    const float psb = ps_b[0];
    fin[0] = r0[0] + r0[1] + r0[2] + r0[3] + psb;
    fin[1] = r1[0] + r1[1] + r1[2] + r1[3] + psb;
    fin[2] = r2[0] + r2[1] + r2[2] + r2[3];
  }
  __syncthreads();
  const float s_off = fin[0], s_diag = fin[1], sent = fin[2];
  if (tid < 129) {
    float v;
    if (tid == 128) v = sent;
    else {
      v = (tid == t) ? s_diag : s_off;
      if (src_mask[b * 128 + tid] == 0) v = NEGV;
    }
    out0[(size_t)bt * 129 + tid] = v;
  }
}

// ---------------- launch ----------------
extern "C" void kernel_launch(void* const* d_in, const int* in_sizes, int n_in,
                              void* d_out, int out_size, void* d_ws, size_t ws_size,
                              hipStream_t stream) {
  const int* src_ids   = (const int*)d_in[0];
  const int* src_mask  = (const int*)d_in[1];
  const int* cmask     = (const int*)d_in[2];
  const float* emb     = (const float*)d_in[3];
  const float* Wih_f   = (const float*)d_in[4];
  const float* Whh_f   = (const float*)d_in[5];
  const float* b_f     = (const float*)d_in[6];
  const float* Wih_b   = (const float*)d_in[7];
  const float* Whh_b   = (const float*)d_in[8];
  const float* b_b     = (const float*)d_in[9];
  const float* Wih_d   = (const float*)d_in[10];
  const float* Whh_d   = (const float*)d_in[11];
  const float* b_d     = (const float*)d_in[12];
  const float* W1      = (const float*)d_in[13];
  const float* W2      = (const float*)d_in[14];
  const float* v_att   = (const float*)d_in[15];
  const float* comb_W  = (const float*)d_in[16];
  const float* comb_b  = (const float*)d_in[17];
  const float* vocab_W = (const float*)d_in[18];
  const float* vocab_b = (const float*)d_in[19];
  const float* Wg_W    = (const float*)d_in[20];
  const float* Wg_b    = (const float*)d_in[21];
  const float* ptr_W   = (const float*)d_in[22];
  const float* ptr_b   = (const float*)d_in[23];
  const float* ps_W    = (const float*)d_in[24];
  const float* ps_b    = (const float*)d_in[25];
  (void)in_sizes; (void)n_in; (void)out_size; (void)ws_size;

  char* wsb = (char*)d_ws;
  size_t o = 0;
  auto alloc = [&](size_t bytes) { char* p = wsb + o; o = (o + bytes + 255) & ~(size_t)255; return p; };
  __hip_bfloat16* xb      = (__hip_bfloat16*)alloc((size_t)BN_ * E_ * 2);
  __hip_bfloat16* xproj16 = (__hip_bfloat16*)alloc((size_t)3 * BN_ * 2048 * 2);
  __hip_bfloat16* ehsb    = (__hip_bfloat16*)alloc((size_t)BN_ * 1024 * 2);
  __hip_bfloat16* ehsT    = (__hip_bfloat16*)alloc((size_t)16 * 1024 * 128 * 2);
  __hip_bfloat16* catb    = (__hip_bfloat16*)alloc((size_t)BN_ * 1536 * 2);
  float* dterm            = (float*)alloc((size_t)BN_ * 512 * 4);
  __hip_bfloat16* etT     = (__hip_bfloat16*)alloc((size_t)16 * 512 * 128 * 2);
  __hip_bfloat16* alphab  = (__hip_bfloat16*)alloc((size_t)BN_ * 128 * 2);
  __hip_bfloat16* combb   = (__hip_bfloat16*)alloc((size_t)BN_ * 512 * 2);
  float* wgout            = (float*)alloc((size_t)BN_ * 512 * 4);
  float* baseb            = (float*)alloc((size_t)BN_ * 128 * 4);
  __hip_bfloat16* hbuf    = (__hip_bfloat16*)alloc((size_t)3 * 128 * 8192 * 2);
  __hip_bfloat16* wihf16  = (__hip_bfloat16*)alloc((size_t)2048 * 384 * 2);
  __hip_bfloat16* wihb16  = (__hip_bfloat16*)alloc((size_t)2048 * 384 * 2);
  __hip_bfloat16* wihd16  = (__hip_bfloat16*)alloc((size_t)2048 * 384 * 2);
  __hip_bfloat16* w1_16   = (__hip_bfloat16*)alloc((size_t)512 * 512 * 2);
  __hip_bfloat16* w2_16   = (__hip_bfloat16*)alloc((size_t)512 * 1024 * 2);
  __hip_bfloat16* combw16 = (__hip_bfloat16*)alloc((size_t)512 * 1536 * 2);
  __hip_bfloat16* vocw16  = (__hip_bfloat16*)alloc((size_t)8000 * 512 * 2);
  __hip_bfloat16* wgw16   = (__hip_bfloat16*)alloc((size_t)512 * 512 * 2);   // 640x512 with ptrw16
  __hip_bfloat16* ptrw16  = (__hip_bfloat16*)alloc((size_t)128 * 512 * 2);   // contiguous after wgw16

  float* out0 = (float*)d_out;
  float* out1 = out0 + (size_t)BN_ * 129;

  hipError_t e0 = hipMemsetAsync(hbuf, 0x7f, (size_t)3 * 128 * 8192 * 2, stream);
  (void)e0;
  embed_kernel<<<BN_, 256, 0, stream>>>(src_ids, emb, xb);

  // cast1: the three Wih (needed by xproj, which precedes the fused kernel)
  CastArgs c1;
  {
    const float* s3[3] = {Wih_f, Wih_b, Wih_d};
    __hip_bfloat16* d3[3] = {wihf16, wihb16, wihd16};
    int acc = 0;
    for (int k = 0; k < 3; ++k) {
      c1.s[k] = s3[k]; c1.d[k] = (unsigned long long)d3[k]; c1.base[k] = acc;
      acc += 2048 * 384;
    }
    for (int k = 3; k < 12; ++k) { c1.s[k] = nullptr; c1.d[k] = 0; c1.base[k] = 0x7fffffff; }
    c1.total = acc; c1.special = -1;
  }
  cast_kernel<<<1024, 256, 0, stream>>>(c1);

  // xproj (bias folded), bf16 out
  bgemm_kernel<0, false><<<dim3(16, 16), 256, 0, stream>>>(
      xb, E_, wihf16, E_, b_f, nullptr, 0, xproj16, 2048, BN_, 2048, E_, nullptr, 0);
  bgemm_kernel<0, false><<<dim3(16, 16), 256, 0, stream>>>(
      xb, E_, wihb16, E_, b_b, nullptr, 0, xproj16 + (size_t)BN_ * 2048, 2048, BN_, 2048, E_, nullptr, 0);
  bgemm_kernel<0, false><<<dim3(16, 16), 256, 0, stream>>>(
      xb, E_, wihd16, E_, b_d, nullptr, 0, xproj16 + (size_t)2 * BN_ * 2048, 2048, BN_, 2048, E_, nullptr, 0);

  // cast2 (runs inside fused kernel, hidden under lstm)
  CastArgs c2;
  {
    const float* s6[6] = {W1, W2, comb_W, vocab_W, Wg_W, ptr_W};
    __hip_bfloat16* d6[6] = {w1_16, w2_16, combw16, vocw16, wgw16, ptrw16};
    int ns[6] = {512 * 512, 512 * 1024, 512 * 1536, 8000 * 512, 512 * 512, 128 * 512};
    int acc = 0;
    for (int k = 0; k < 6; ++k) {
      c2.s[k] = s6[k]; c2.d[k] = (unsigned long long)d6[k]; c2.base[k] = acc;
      acc += ns[k];
    }
    for (int k = 6; k < 12; ++k) { c2.s[k] = nullptr; c2.d[k] = 0; c2.base[k] = 0x7fffffff; }
    c2.total = acc; c2.special = 5;
  }

  hipError_t e1 = hipFuncSetAttribute((const void*)fused_kernel,
                      hipFuncAttributeMaxDynamicSharedMemorySize, 82432);
  (void)e1;
  fused_kernel<<<544, 256, 82432, stream>>>(
      xproj16, Whh_f, Whh_b, Whh_d, hbuf, ehsb, ehsT, catb, c2);

  // dterm = 2 * dec_h @ W1^T (f32) ; etT = 2 * transposed bf16 eterm
  bgemm64_kernel<2, 0><<<dim3(8, 32), 256, 0, stream>>>(
      catb, 1536, w1_16, 512, nullptr, nullptr, dterm, 512, nullptr, nullptr, 0,
      BN_, 512, 512, 0, 0, 0);
  bgemm64_kernel<2, 1><<<dim3(8, 32), 256, 0, stream>>>(
      ehsb, 1024, w2_16, 1024, nullptr, nullptr, nullptr, 0, nullptr, etT, 0,
      BN_, 512, 1024, 0, 0, 0);

  score_kernel<<<16 * 32, 256, 0, stream>>>(dterm, etT, v_att, src_mask, alphab);

  // context = alpha[b] @ ehsT[b]^T -> catb[:,512:1536]
  bgemm64_kernel<0, 0><<<dim3(16, 2, 16), 256, 0, stream>>>(
      alphab, 128, ehsT, 128, nullptr, nullptr, nullptr, 0, nullptr,
      catb + 512, 1536, 128, 1024, 128, 128 * 128, 1024 * 128, 128 * 1536);

  // combined = tanh(cat @ comb_W^T + comb_b) -> bf16
  bgemm64_kernel<1, 0><<<dim3(8, 32), 256, 0, stream>>>(
      catb, 1536, combw16, 1536, comb_b, nullptr, nullptr, 0, nullptr,
      combb, 512, BN_, 512, 1536, 0, 0, 0);

  // vocab logits + confusionset mask
  bgemm_kernel<0, true><<<dim3(63, 16), 256, 0, stream>>>(
      combb, 512, vocw16, 512, vocab_b, out1, V_, nullptr, 0, BN_, V_, 512, cmask, V_);

  // fused wg/base
  bgemm64_kernel<0, 2><<<dim3(10, 32), 256, 0, stream>>>(
      combb, 512, wgw16, 512, Wg_b, ptr_b, wgout, 512, baseb, nullptr, 0,
      BN_, 640, 512, 0, 0, 0);

  pointer_kernel<<<BN_, 256, 0, stream>>>(baseb, wgout, ptr_W, ps_W, ps_b, src_mask, out0);
}

// Round 10
// 605.628 us; speedup vs baseline: 1.2121x; 1.2121x over previous
//
#include <hip/hip_runtime.h>
#include <hip/hip_bf16.h>
#include <math.h>

#define NEGV -1000000000.0f

static constexpr int B_ = 16, N_ = 128, BN_ = 2048;
static constexpr int E_ = 384, V_ = 8000;

typedef __attribute__((ext_vector_type(8))) short short8v;
typedef __attribute__((ext_vector_type(4))) float f32x4;

// ---------------- helpers ----------------
__device__ inline float wave_sum(float v) {
#pragma unroll
  for (int o = 32; o; o >>= 1) v += __shfl_xor(v, o);
  return v;
}
__device__ inline float wave_max(float v) {
#pragma unroll
  for (int o = 32; o; o >>= 1) v = fmaxf(v, __shfl_xor(v, o));
  return v;
}
__device__ inline float fast_tanh(float x) {
  return 1.f - 2.f / (1.f + __expf(2.f * x));
}
__device__ inline float fast_tanh_pre(float x2) {  // input pre-scaled by 2
  return 1.f - 2.f / (1.f + __expf(x2));
}
__device__ inline float fast_sig(float x) {
  return 1.f / (1.f + __expf(-x));
}
__device__ __forceinline__ void gl16(const void* g, void* l) {
  __builtin_amdgcn_global_load_lds((const __attribute__((address_space(1))) void*)g,
                                   (__attribute__((address_space(3))) void*)l, 16, 0, 0);
}

// ---------------- embedding gather -> bf16 ----------------
__global__ __launch_bounds__(256) void embed_kernel(
    const int* __restrict__ ids, const float* __restrict__ emb,
    __hip_bfloat16* __restrict__ xb) {
  const int row = blockIdx.x;
  const int id = ids[row];
  for (int e = threadIdx.x; e < E_; e += 256)
    xb[(size_t)row * E_ + e] = __float2bfloat16(emb[(size_t)id * E_ + e]);
}

// ---------------- multi-segment fp32 -> bf16 cast ----------------
struct CastArgs {
  const float* s[12];
  unsigned long long d[12];
  int base[12];
  int total;
  int special;  // segment index with ptr_W [128][513]->[128][512] packing, or -1
};
__device__ inline void cast_body(const CastArgs& a, int gsize, int gid0) {
  const int nq = a.total >> 2;
  for (int q = gid0; q < nq; q += gsize) {
    const int e = q << 2;
    int k = 11;
    while (e < a.base[k]) --k;
    const int i = e - a.base[k];
    __hip_bfloat16* dst = (__hip_bfloat16*)a.d[k] + i;
    if (k == a.special) {
      const int row = i >> 9, col = i & 511;
      const float* sp = a.s[k] + (size_t)row * 513 + col;
#pragma unroll
      for (int u = 0; u < 4; ++u) dst[u] = __float2bfloat16(sp[u]);
    } else {
      float4 v = *(const float4*)(a.s[k] + i);
      __hip_bfloat16 h0 = __float2bfloat16(v.x), h1 = __float2bfloat16(v.y);
      __hip_bfloat16 h2 = __float2bfloat16(v.z), h3 = __float2bfloat16(v.w);
      ushort4 u4 = {*(unsigned short*)&h0, *(unsigned short*)&h1,
                    *(unsigned short*)&h2, *(unsigned short*)&h3};
      *(ushort4*)dst = u4;
    }
  }
}
__global__ __launch_bounds__(256) void cast_kernel(CastArgs a) {
  cast_body(a, gridDim.x * 256, blockIdx.x * 256 + threadIdx.x);
}

// ---------------- 128x128-tile bf16 MFMA GEMM (big GEMMs) ----------------
template <int ACT, bool MASK>
__global__ __launch_bounds__(256) void bgemm_kernel(
    const __hip_bfloat16* __restrict__ A, int lda,
    const __hip_bfloat16* __restrict__ W, int ldw,
    const float* __restrict__ bias,
    float* __restrict__ C, int ldc,
    __hip_bfloat16* __restrict__ Cb, int ldcb,
    int M, int N, int K,
    const int* __restrict__ mask, int ldm) {
  __shared__ __hip_bfloat16 Al[2][4096];
  __shared__ __hip_bfloat16 Bl[2][4096];
  const int tid = threadIdx.x;
  const int wid = tid >> 6, lane = tid & 63;
  const int m0 = blockIdx.y * 128, n0 = blockIdx.x * 128;
  const int nkt = K >> 5;
  const int rm = (wid >> 1) << 6, rn = (wid & 1) << 6;
  const int lrow = lane & 15, kq = lane >> 4;
  const int fs = ((lrow >> 1) & 3) << 4;

  f32x4 acc[4][4];
#pragma unroll
  for (int i = 0; i < 4; ++i)
#pragma unroll
    for (int j = 0; j < 4; ++j) acc[i][j] = {0.f, 0.f, 0.f, 0.f};

  auto stage = [&](int bi, int kt) {
#pragma unroll
    for (int c = 0; c < 2; ++c) {
      const int p = ((c * 4 + wid) << 6) + lane;
      const int row = p >> 2, cb = (p & 3) << 4;
      const int sw = ((row >> 1) & 3) << 4;
      const unsigned loff = (unsigned)__builtin_amdgcn_readfirstlane((c * 4 + wid) << 10);
      {
        const char* src = (const char*)A + ((size_t)(m0 + row) * lda + (size_t)kt * 32) * 2 + (cb ^ sw);
        gl16(src, (char*)&Al[bi][0] + loff);
      }
      {
        int gr = n0 + row;
        if (gr >= N) gr = N - 1;
        const char* src = (const char*)W + ((size_t)gr * ldw + (size_t)kt * 32) * 2 + (cb ^ sw);
        gl16(src, (char*)&Bl[bi][0] + loff);
      }
    }
  };
  auto compute = [&](int bi) {
    const char* Ab = (const char*)&Al[bi][0];
    const char* Bb = (const char*)&Bl[bi][0];
    const int roff = (kq << 4) ^ fs;
    short8v a[4], b[4];
#pragma unroll
    for (int i = 0; i < 4; ++i)
      a[i] = *(const short8v*)(Ab + (rm + i * 16 + lrow) * 64 + roff);
#pragma unroll
    for (int j = 0; j < 4; ++j)
      b[j] = *(const short8v*)(Bb + (rn + j * 16 + lrow) * 64 + roff);
#pragma unroll
    for (int i = 0; i < 4; ++i)
#pragma unroll
      for (int j = 0; j < 4; ++j)
        acc[i][j] = __builtin_amdgcn_mfma_f32_16x16x32_bf16(a[i], b[j], acc[i][j], 0, 0, 0);
  };

  stage(0, 0);
  for (int kt = 0; kt < nkt; ++kt) {
    __syncthreads();
    if (kt + 1 < nkt) stage((kt + 1) & 1, kt + 1);
    compute(kt & 1);
  }

#pragma unroll
  for (int i = 0; i < 4; ++i) {
#pragma unroll
    for (int r = 0; r < 4; ++r) {
      const int m = m0 + rm + i * 16 + kq * 4 + r;
#pragma unroll
      for (int j = 0; j < 4; ++j) {
        const int n = n0 + rn + j * 16 + lrow;
        if (n < N) {
          float v = acc[i][j][r] + (bias ? bias[n] : 0.f);
          if (ACT == 1) v = fast_tanh(v);
          if (MASK) {
            if (mask[(size_t)m * ldm + n] == 0) v = NEGV;
          }
          if (C) C[(size_t)m * ldc + n] = v;
          if (Cb) Cb[(size_t)m * ldcb + n] = __float2bfloat16(v);
        }
      }
    }
  }
}

// ---------------- 64x64-tile bf16 MFMA GEMM ----------------
// ACT: 0 none, 1 tanh(v+bias), 2 v*=2 (prescale for score)
// TROUT: 0 normal, 1 etT transposed-out, 2 split wg(tanh,f32)/base(raw,f32)
template <int ACT, int TROUT>
__global__ __launch_bounds__(256) void bgemm64_kernel(
    const __hip_bfloat16* __restrict__ A, int lda,
    const __hip_bfloat16* __restrict__ W, int ldw,
    const float* __restrict__ bias, const float* __restrict__ bias2,
    float* __restrict__ C, int ldc, float* __restrict__ C2,
    __hip_bfloat16* __restrict__ Cb, int ldcb,
    int M, int N, int K,
    long aBs, long wBs, long cBs) {
  __shared__ __hip_bfloat16 Al[2][2048];
  __shared__ __hip_bfloat16 Bl[2][2048];
  A += (size_t)blockIdx.z * aBs;
  W += (size_t)blockIdx.z * wBs;
  const int tid = threadIdx.x;
  const int wid = tid >> 6, lane = tid & 63;
  const int m0 = blockIdx.y * 64, n0 = blockIdx.x * 64;
  const int nkt = K >> 5;
  const int rm = (wid >> 1) << 5, rn = (wid & 1) << 5;
  const int lrow = lane & 15, kq = lane >> 4;
  const int fs = ((lrow >> 1) & 3) << 4;

  f32x4 acc[2][2];
#pragma unroll
  for (int i = 0; i < 2; ++i)
#pragma unroll
    for (int j = 0; j < 2; ++j) acc[i][j] = {0.f, 0.f, 0.f, 0.f};

  auto stage = [&](int bi, int kt) {
    const int p = tid;
    const int row = p >> 2, cb = (p & 3) << 4;
    const int sw = ((row >> 1) & 3) << 4;
    const unsigned loff = (unsigned)__builtin_amdgcn_readfirstlane(wid << 10);
    {
      const char* src = (const char*)A + ((size_t)(m0 + row) * lda + (size_t)kt * 32) * 2 + (cb ^ sw);
      gl16(src, (char*)&Al[bi][0] + loff);
    }
    {
      const char* src = (const char*)W + ((size_t)(n0 + row) * ldw + (size_t)kt * 32) * 2 + (cb ^ sw);
      gl16(src, (char*)&Bl[bi][0] + loff);
    }
  };
  auto compute = [&](int bi) {
    const char* Ab = (const char*)&Al[bi][0];
    const char* Bb = (const char*)&Bl[bi][0];
    const int roff = (kq << 4) ^ fs;
    short8v a[2], b[2];
#pragma unroll
    for (int i = 0; i < 2; ++i)
      a[i] = *(const short8v*)(Ab + (rm + i * 16 + lrow) * 64 + roff);
#pragma unroll
    for (int j = 0; j < 2; ++j)
      b[j] = *(const short8v*)(Bb + (rn + j * 16 + lrow) * 64 + roff);
#pragma unroll
    for (int i = 0; i < 2; ++i)
#pragma unroll
      for (int j = 0; j < 2; ++j)
        acc[i][j] = __builtin_amdgcn_mfma_f32_16x16x32_bf16(a[i], b[j], acc[i][j], 0, 0, 0);
  };

  stage(0, 0);
  for (int kt = 0; kt < nkt; ++kt) {
    __syncthreads();
    if (kt + 1 < nkt) stage((kt + 1) & 1, kt + 1);
    compute(kt & 1);
  }

#pragma unroll
  for (int i = 0; i < 2; ++i) {
#pragma unroll
    for (int r = 0; r < 4; ++r) {
      const int m = m0 + rm + i * 16 + kq * 4 + r;
#pragma unroll
      for (int j = 0; j < 2; ++j) {
        const int n = n0 + rn + j * 16 + lrow;
        float v = acc[i][j][r];
        if (TROUT == 2) {
          if (n < 512) {
            C[(size_t)m * ldc + n] = fast_tanh(v + bias[n]);
          } else {
            C2[(size_t)m * 128 + (n - 512)] = v + bias2[n - 512];
          }
        } else {
          if (ACT == 2) v *= 2.f;
          else {
            v += (bias ? bias[n] : 0.f);
            if (ACT == 1) v = fast_tanh(v);
          }
          if (TROUT == 1) {
            Cb[(((size_t)(m >> 7) * 512 + n) << 7) + (m & 127)] = __float2bfloat16(v);
          } else {
            if (C) C[(size_t)m * ldc + n] = v;
            if (Cb) Cb[(size_t)m * ldcb + n + (size_t)blockIdx.z * cBs] = __float2bfloat16(v);
          }
        }
      }
    }
  }
}

// ---------------- FUSED: lstm (96 blocks) + cast2 (64 blocks) ----------------
// lstm: two-phase poll (ushort sentinel probe -> 64B line fetch); 512B publish
// via ONE exec-masked wave-wide store (sector-atomic), wave-rotated so the
// store-ack hits each wave 1-in-4 steps; own-block region via LDS. Every step's
// h also recorded in an LDS history [128][16b][16d]; after the loop each block
// writes its own ehsb/ehsT/catb slice (NO separate scatter kernel, no polling
// consumers hammering the coherence point — the R9 regression).
// dyn LDS: W 64K + h 16K + hout 512 + hist 64K = 147968 B (fits 160K pool).
__global__ __launch_bounds__(256) void fused_kernel(
    const __hip_bfloat16* __restrict__ xp16,   // [3][2048][2048]
    const float* __restrict__ whhF, const float* __restrict__ whhB,
    const float* __restrict__ whhD,
    __hip_bfloat16* __restrict__ hbuf,         // [3][128][32][16b][16d]
    __hip_bfloat16* __restrict__ ehsb, __hip_bfloat16* __restrict__ ehsT,
    __hip_bfloat16* __restrict__ catb,
    CastArgs ca2) {
  extern __shared__ char sm[];
  const int bid = blockIdx.x;
  const int tid = threadIdx.x;

  if (bid >= 96) {  // ---- cast2 role (plain reads, no polling) ----
    cast_body(ca2, 64 * 256, (bid - 96) * 256 + tid);
    return;
  }

  // ---- LSTM role ----
  const int l = bid >> 5, g = bid & 31;
  const int lane = tid & 63, wid = tid >> 6;
  char* smW = sm;                                   // 65536
  char* smH = sm + 65536;                           // 16384
  __hip_bfloat16* hout = (__hip_bfloat16*)(sm + 65536 + 16384);  // 512
  char* hist = sm + 65536 + 16384 + 512;            // 65536: [s][b][d] ushort

  // stage weights from f32, reordered dim-major: LDS row lr = d_local*4 + gate
  const float* wsrc = (l == 0) ? whhF : ((l == 1) ? whhB : whhD);
  auto cv = [](float x) -> unsigned {
    __hip_bfloat16 h = __float2bfloat16(x);
    return (unsigned)*(unsigned short*)&h;
  };
  for (int p = tid; p < 4096; p += 256) {
    const int r = p >> 6, cb = (p & 63) << 4;
    const int grow = (r & 3) * 512 + (g << 4) + (r >> 2);
    const float* srcp = wsrc + (size_t)grow * 512 + ((p & 63) << 3);
    float4 u0 = *(const float4*)srcp;
    float4 u1 = *(const float4*)(srcp + 4);
    uint4 q;
    q.x = cv(u0.x) | (cv(u0.y) << 16);
    q.y = cv(u0.z) | (cv(u0.w) << 16);
    q.z = cv(u1.x) | (cv(u1.y) << 16);
    q.w = cv(u1.z) | (cv(u1.w) << 16);
    *(uint4*)(smW + r * 1024 + (cb ^ ((r & 7) << 4))) = q;
  }

  const int lrow = lane & 15, kq = lane >> 4;
  const int swz = (lrow & 7) << 4;
  const char* aB = smW + (wid * 16 + lrow) * 1024;
  const char* bB = smH + lrow * 1024;
  const int dl16 = wid * 4 + kq;
  const int dg = (g << 4) + dl16;
  const int bb = lrow;
  const bool rev = (l == 1);
  const __hip_bfloat16* xl = xp16 + (size_t)l * 2048 * 2048;
  __hip_bfloat16* hb_l = hbuf + (size_t)l * 128 * 8192;
  const int gq = tid >> 3;
  const int b0 = (tid & 7) * 2;
  const int gb = gq * 32;
  const int sw0 = (b0 & 7) << 4, sw1 = ((b0 + 1) & 7) << 4;
  float c = 0.f;

  for (int s = 0; s < 128; ++s) {
    const int t = rev ? 127 - s : s;
    const size_t xro = (size_t)(bb * 128 + t) * 2048 + dg;
    const float xgi = __bfloat162float(xl[xro]);
    const float xgf = __bfloat162float(xl[xro + 512]);
    const float xgg = __bfloat162float(xl[xro + 1024]);
    const float xgo = __bfloat162float(xl[xro + 1536]);

    if (s > 0) {
      if (gq != g) {
        const char* hsrc = (const char*)(hb_l + (size_t)(s - 1) * 8192);
        const unsigned loff = (unsigned)(tid * 64);
        unsigned hv;
        while (true) {
          asm volatile(
              "global_load_ushort %0, %1, %2 sc0 sc1\n\t"
              "s_waitcnt vmcnt(0)"
              : "=&v"(hv) : "v"(loff), "s"(hsrc) : "memory");
          if ((hv & 0xffffu) != 0x7f7fu) break;
          __builtin_amdgcn_s_sleep(1);
        }
        f32x4 q0, q1, q2, q3;
        asm volatile(
            "global_load_dwordx4 %0, %4, %5 sc0 sc1\n\t"
            "global_load_dwordx4 %1, %4, %5 offset:16 sc0 sc1\n\t"
            "global_load_dwordx4 %2, %4, %5 offset:32 sc0 sc1\n\t"
            "global_load_dwordx4 %3, %4, %5 offset:48 sc0 sc1\n\t"
            "s_waitcnt vmcnt(0)"
            : "=&v"(q0), "=&v"(q1), "=&v"(q2), "=&v"(q3)
            : "v"(loff), "s"(hsrc) : "memory");
        *(f32x4*)(smH + b0 * 1024 + (gb ^ sw0)) = q0;
        *(f32x4*)(smH + b0 * 1024 + ((gb + 16) ^ sw0)) = q1;
        *(f32x4*)(smH + (b0 + 1) * 1024 + (gb ^ sw1)) = q2;
        *(f32x4*)(smH + (b0 + 1) * 1024 + ((gb + 16) ^ sw1)) = q3;
      } else {
        // own region: copy prev-step h from hout (LDS), no global RT
        const char* hl = (const char*)hout + b0 * 32;
        f32x4 c0 = *(const f32x4*)(hl);
        f32x4 c1 = *(const f32x4*)(hl + 16);
        f32x4 c2 = *(const f32x4*)(hl + 32);
        f32x4 c3 = *(const f32x4*)(hl + 48);
        *(f32x4*)(smH + b0 * 1024 + (gb ^ sw0)) = c0;
        *(f32x4*)(smH + b0 * 1024 + ((gb + 16) ^ sw0)) = c1;
        *(f32x4*)(smH + (b0 + 1) * 1024 + (gb ^ sw1)) = c2;
        *(f32x4*)(smH + (b0 + 1) * 1024 + ((gb + 16) ^ sw1)) = c3;
      }
    } else {
      const f32x4 z = {0.f, 0.f, 0.f, 0.f};
      *(f32x4*)(smH + b0 * 1024 + (gb ^ sw0)) = z;
      *(f32x4*)(smH + b0 * 1024 + ((gb + 16) ^ sw0)) = z;
      *(f32x4*)(smH + (b0 + 1) * 1024 + (gb ^ sw1)) = z;
      *(f32x4*)(smH + (b0 + 1) * 1024 + ((gb + 16) ^ sw1)) = z;
    }
    __syncthreads();  // A: smH fully staged

    f32x4 acc0 = {0.f, 0.f, 0.f, 0.f}, acc1 = {0.f, 0.f, 0.f, 0.f};
#pragma unroll
    for (int kt = 0; kt < 16; kt += 2) {
      const int off0 = ((kt * 64 + (kq << 4)) ^ swz);
      const int off1 = (((kt + 1) * 64 + (kq << 4)) ^ swz);
      short8v a0 = *(const short8v*)(aB + off0);
      short8v b0v = *(const short8v*)(bB + off0);
      short8v a1 = *(const short8v*)(aB + off1);
      short8v b1v = *(const short8v*)(bB + off1);
      acc0 = __builtin_amdgcn_mfma_f32_16x16x32_bf16(a0, b0v, acc0, 0, 0, 0);
      acc1 = __builtin_amdgcn_mfma_f32_16x16x32_bf16(a1, b1v, acc1, 0, 0, 0);
    }
    const f32x4 acc = acc0 + acc1;  // acc[r] = gate r for (dg, bb)

    const float gi = acc[0] + xgi;
    const float gf = acc[1] + xgf;
    const float gg = acc[2] + xgg;
    const float go = acc[3] + xgo;
    c = fmaf(fast_sig(gf), c, fast_sig(gi) * fast_tanh(gg));
    const float h = fast_sig(go) * fast_tanh(c);
    __hip_bfloat16 hb16 = __float2bfloat16(h);
    const unsigned short hraw = *(unsigned short*)&hb16;
    hout[bb * 16 + dl16] = hb16;
    *(unsigned short*)(hist + s * 512 + (bb * 16 + dl16) * 2) = hraw;  // history
    __syncthreads();  // B: MFMA reads done + hout complete

    // publish: ONE wave-wide store instruction (sector-atomic), wave rotates
    if (s < 127 && wid == (s & 3) && (lane < 32)) {
      f32x4 hv4 = *(const f32x4*)((const char*)hout + lane * 16);
      char* hdst = (char*)(hb_l + (size_t)s * 8192);
      asm volatile("global_store_dwordx4 %0, %1, %2 sc0 sc1"
                   :: "v"((unsigned)((g << 9) + lane * 16)), "v"(hv4), "s"(hdst)
                   : "memory");
    }
    // no drain: ack folds into that wave's next poll vmcnt (1-in-4 steps)
  }

  // ---- epilogue: write own slice of ehsb/ehsT/catb from LDS history ----
  __syncthreads();
  const int bb2 = tid >> 4, lo2 = tid & 15;
  if (l < 2) {
    // ehsT[b][l*512 + g*16 + d][t], t contiguous; thread = (bb2, dl2=lo2)
    const int hoff = (bb2 * 16 + lo2) * 2;
    char* dstT = (char*)(ehsT + ((size_t)bb2 * 1024 + l * 512 + (g << 4) + lo2) * 128);
    for (int tc = 0; tc < 128; tc += 32) {
      unsigned v[16];
#pragma unroll
      for (int w = 0; w < 16; ++w) {
        const int t0 = tc + 2 * w;
        const int s0 = rev ? 127 - t0 : t0;
        const int s1 = rev ? 126 - t0 : t0 + 1;
        unsigned a = *(const unsigned short*)(hist + s0 * 512 + hoff);
        unsigned b2 = *(const unsigned short*)(hist + s1 * 512 + hoff);
        v[w] = a | (b2 << 16);
      }
#pragma unroll
      for (int q = 0; q < 4; ++q)
        *(uint4*)(dstT + tc * 2 + q * 16) =
            make_uint4(v[q * 4], v[q * 4 + 1], v[q * 4 + 2], v[q * 4 + 3]);
    }
    // ehsb[b*128+t][l*512 + g*16 .. +16]; thread = (bb2, 8 t's)
    for (int k = 0; k < 8; ++k) {
      const int t = lo2 * 8 + k;
      const int s0 = rev ? 127 - t : t;
      const char* srcp = hist + s0 * 512 + bb2 * 32;
      uint4 ra = *(const uint4*)srcp;
      uint4 rb = *(const uint4*)(srcp + 16);
      char* dp = (char*)(ehsb + ((size_t)(bb2 * 128 + t)) * 1024 + l * 512 + (g << 4));
      *(uint4*)dp = ra;
      *(uint4*)(dp + 16) = rb;
    }
  } else {
    for (int k = 0; k < 8; ++k) {
      const int t = lo2 * 8 + k;  // l==2: rev=false, s==t
      const char* srcp = hist + t * 512 + bb2 * 32;
      uint4 ra = *(const uint4*)srcp;
      uint4 rb = *(const uint4*)(srcp + 16);
      char* dp = (char*)(catb + ((size_t)(bb2 * 128 + t)) * 1536 + (g << 4));
      *(uint4*)dp = ra;
      *(uint4*)(dp + 16) = rb;
    }
  }
}

// ---------------- score + softmax -> alpha; 4 t's per block ----------------
// dterm/etT are pre-scaled by 2: tanh(d+e) = 1 - 2/(1+exp(d'+e'))
__global__ __launch_bounds__(256) void score_kernel(
    const float* __restrict__ dterm, const __hip_bfloat16* __restrict__ etT,
    const float* __restrict__ v_att, const int* __restrict__ src_mask,
    __hip_bfloat16* __restrict__ alphab) {
  const int b = blockIdx.x >> 5, tg = blockIdx.x & 31;
  const int t0 = tg * 4;
  const int tid = threadIdx.x;
  __shared__ float dt[4][512], vs[512], red[4][4][128], al[4][128];
  for (int i = tid; i < 2048; i += 256)
    dt[i >> 9][i & 511] = dterm[((size_t)(b * 128 + t0 + (i >> 9))) * 512 + (i & 511)];
  vs[tid] = v_att[tid];
  vs[tid + 256] = v_att[256 + tid];
  __syncthreads();
  const int n0 = (tid & 63) << 1, ah = tid >> 6;
  {
    const __hip_bfloat16* ep = etT + (((size_t)b * 512 + ah * 128) << 7) + n0;
    const float* vp = vs + ah * 128;
    const float* dp0 = &dt[0][ah * 128];
    const float* dp1 = &dt[1][ah * 128];
    const float* dp2 = &dt[2][ah * 128];
    const float* dp3 = &dt[3][ah * 128];
    float p00 = 0, p01 = 0, p10 = 0, p11 = 0, p20 = 0, p21 = 0, p30 = 0, p31 = 0;
    for (int a = 0; a < 128; ++a) {
      const unsigned u = *(const unsigned*)(ep + ((size_t)a << 7));
      unsigned u0 = u << 16, u1 = u & 0xffff0000u;
      const float e0 = __builtin_bit_cast(float, u0);
      const float e1 = __builtin_bit_cast(float, u1);
      const float va = vp[a];
      p00 = fmaf(va, fast_tanh_pre(dp0[a] + e0), p00);
      p01 = fmaf(va, fast_tanh_pre(dp0[a] + e1), p01);
      p10 = fmaf(va, fast_tanh_pre(dp1[a] + e0), p10);
      p11 = fmaf(va, fast_tanh_pre(dp1[a] + e1), p11);
      p20 = fmaf(va, fast_tanh_pre(dp2[a] + e0), p20);
      p21 = fmaf(va, fast_tanh_pre(dp2[a] + e1), p21);
      p30 = fmaf(va, fast_tanh_pre(dp3[a] + e0), p30);
      p31 = fmaf(va, fast_tanh_pre(dp3[a] + e1), p31);
    }
    red[0][ah][n0] = p00; red[0][ah][n0 + 1] = p01;
    red[1][ah][n0] = p10; red[1][ah][n0 + 1] = p11;
    red[2][ah][n0] = p20; red[2][ah][n0 + 1] = p21;
    red[3][ah][n0] = p30; red[3][ah][n0 + 1] = p31;
  }
  __syncthreads();
#pragma unroll
  for (int tp = 0; tp < 2; ++tp) {
    const int tt = tp * 2 + (tid >> 7);
    const int n = tid & 127;
    float sc = red[tt][0][n] + red[tt][1][n] + red[tt][2][n] + red[tt][3][n];
    if (src_mask[b * 128 + n] == 0) sc = NEGV;
    al[tt][n] = sc;
  }
  __syncthreads();
  {
    const int tt = tid >> 6, lane = tid & 63;
    const float v0 = al[tt][lane], v1 = al[tt][lane + 64];
    const float m = wave_max(fmaxf(v0, v1));
    const float e0 = __expf(v0 - m), e1 = __expf(v1 - m);
    const float inv = 1.f / wave_sum(e0 + e1);
    __hip_bfloat16* ap = alphab + ((size_t)(b * 128 + t0 + tt)) * 128;
    ap[lane] = __float2bfloat16(e0 * inv);
    ap[lane + 64] = __float2bfloat16(e1 * inv);
  }
}

// ---------------- pointer head assembly ----------------
__global__ __launch_bounds__(256) void pointer_kernel(
    const float* __restrict__ base, const float* __restrict__ wgout,
    const float* __restrict__ ptr_W, const float* __restrict__ ps_W,
    const float* __restrict__ ps_b, const int* __restrict__ src_mask,
    float* __restrict__ out0) {
  const int bt = blockIdx.x;
  const int b = bt >> 7, t = bt & 127;
  const int tid = threadIdx.x;
  __shared__ float r0[4], r1[4], r2[4], fin[3];
  float off_p = 0.f, diag_p = 0.f, sent_p;
  if (tid < 128) {
    const float ba = base[(size_t)bt * 128 + tid];
    const float pw = ps_W[tid];
    off_p = tanhf(ba) * pw;
    diag_p = tanhf(ba + ptr_W[tid * 513 + 512]) * pw;
  }
  sent_p = wgout[(size_t)bt * 512 + tid] + wgout[(size_t)bt * 512 + 256 + tid];
  off_p = wave_sum(off_p);
  diag_p = wave_sum(diag_p);
  sent_p = wave_sum(sent_p);
  const int wid = tid >> 6, lane = tid & 63;
  if (lane == 0) { r0[wid] = off_p; r1[wid] = diag_p; r2[wid] = sent_p; }
  __syncthreads();
  if (tid == 0) {
    const float psb = ps_b[0];
    fin[0] = r0[0] + r0[1] + r0[2] + r0[3] + psb;
    fin[1] = r1[0] + r1[1] + r1[2] + r1[3] + psb;
    fin[2] = r2[0] + r2[1] + r2[2] + r2[3];
  }
  __syncthreads();
  const float s_off = fin[0], s_diag = fin[1], sent = fin[2];
  if (tid < 129) {
    float v;
    if (tid == 128) v = sent;
    else {
      v = (tid == t) ? s_diag : s_off;
      if (src_mask[b * 128 + tid] == 0) v = NEGV;
    }
    out0[(size_t)bt * 129 + tid] = v;
  }
}

// ---------------- launch ----------------
extern "C" void kernel_launch(void* const* d_in, const int* in_sizes, int n_in,
                              void* d_out, int out_size, void* d_ws, size_t ws_size,
                              hipStream_t stream) {
  const int* src_ids   = (const int*)d_in[0];
  const int* src_mask  = (const int*)d_in[1];
  const int* cmask     = (const int*)d_in[2];
  const float* emb     = (const float*)d_in[3];
  const float* Wih_f   = (const float*)d_in[4];
  const float* Whh_f   = (const float*)d_in[5];
  const float* b_f     = (const float*)d_in[6];
  const float* Wih_b   = (const float*)d_in[7];
  const float* Whh_b   = (const float*)d_in[8];
  const float* b_b     = (const float*)d_in[9];
  const float* Wih_d   = (const float*)d_in[10];
  const float* Whh_d   = (const float*)d_in[11];
  const float* b_d     = (const float*)d_in[12];
  const float* W1      = (const float*)d_in[13];
  const float* W2      = (const float*)d_in[14];
  const float* v_att   = (const float*)d_in[15];
  const float* comb_W  = (const float*)d_in[16];
  const float* comb_b  = (const float*)d_in[17];
  const float* vocab_W = (const float*)d_in[18];
  const float* vocab_b = (const float*)d_in[19];
  const float* Wg_W    = (const float*)d_in[20];
  const float* Wg_b    = (const float*)d_in[21];
  const float* ptr_W   = (const float*)d_in[22];
  const float* ptr_b   = (const float*)d_in[23];
  const float* ps_W    = (const float*)d_in[24];
  const float* ps_b    = (const float*)d_in[25];
  (void)in_sizes; (void)n_in; (void)out_size; (void)ws_size;

  char* wsb = (char*)d_ws;
  size_t o = 0;
  auto alloc = [&](size_t bytes) { char* p = wsb + o; o = (o + bytes + 255) & ~(size_t)255; return p; };
  __hip_bfloat16* xb      = (__hip_bfloat16*)alloc((size_t)BN_ * E_ * 2);
  __hip_bfloat16* xproj16 = (__hip_bfloat16*)alloc((size_t)3 * BN_ * 2048 * 2);
  __hip_bfloat16* ehsb    = (__hip_bfloat16*)alloc((size_t)BN_ * 1024 * 2);
  __hip_bfloat16* ehsT    = (__hip_bfloat16*)alloc((size_t)16 * 1024 * 128 * 2);
  __hip_bfloat16* catb    = (__hip_bfloat16*)alloc((size_t)BN_ * 1536 * 2);
  float* dterm            = (float*)alloc((size_t)BN_ * 512 * 4);
  __hip_bfloat16* etT     = (__hip_bfloat16*)alloc((size_t)16 * 512 * 128 * 2);
  __hip_bfloat16* alphab  = (__hip_bfloat16*)alloc((size_t)BN_ * 128 * 2);
  __hip_bfloat16* combb   = (__hip_bfloat16*)alloc((size_t)BN_ * 512 * 2);
  float* wgout            = (float*)alloc((size_t)BN_ * 512 * 4);
  float* baseb            = (float*)alloc((size_t)BN_ * 128 * 4);
  __hip_bfloat16* hbuf    = (__hip_bfloat16*)alloc((size_t)3 * 128 * 8192 * 2);
  __hip_bfloat16* wihf16  = (__hip_bfloat16*)alloc((size_t)2048 * 384 * 2);
  __hip_bfloat16* wihb16  = (__hip_bfloat16*)alloc((size_t)2048 * 384 * 2);
  __hip_bfloat16* wihd16  = (__hip_bfloat16*)alloc((size_t)2048 * 384 * 2);
  __hip_bfloat16* w1_16   = (__hip_bfloat16*)alloc((size_t)512 * 512 * 2);
  __hip_bfloat16* w2_16   = (__hip_bfloat16*)alloc((size_t)512 * 1024 * 2);
  __hip_bfloat16* combw16 = (__hip_bfloat16*)alloc((size_t)512 * 1536 * 2);
  __hip_bfloat16* vocw16  = (__hip_bfloat16*)alloc((size_t)8000 * 512 * 2);
  __hip_bfloat16* wgw16   = (__hip_bfloat16*)alloc((size_t)512 * 512 * 2);   // 640x512 with ptrw16
  __hip_bfloat16* ptrw16  = (__hip_bfloat16*)alloc((size_t)128 * 512 * 2);   // contiguous after wgw16

  float* out0 = (float*)d_out;
  float* out1 = out0 + (size_t)BN_ * 129;

  hipError_t e0 = hipMemsetAsync(hbuf, 0x7f, (size_t)3 * 128 * 8192 * 2, stream);
  (void)e0;
  embed_kernel<<<BN_, 256, 0, stream>>>(src_ids, emb, xb);

  // cast1: the three Wih (needed by xproj, which precedes the fused kernel)
  CastArgs c1;
  {
    const float* s3[3] = {Wih_f, Wih_b, Wih_d};
    __hip_bfloat16* d3[3] = {wihf16, wihb16, wihd16};
    int acc = 0;
    for (int k = 0; k < 3; ++k) {
      c1.s[k] = s3[k]; c1.d[k] = (unsigned long long)d3[k]; c1.base[k] = acc;
      acc += 2048 * 384;
    }
    for (int k = 3; k < 12; ++k) { c1.s[k] = nullptr; c1.d[k] = 0; c1.base[k] = 0x7fffffff; }
    c1.total = acc; c1.special = -1;
  }
  cast_kernel<<<1024, 256, 0, stream>>>(c1);

  // xproj (bias folded), bf16 out
  bgemm_kernel<0, false><<<dim3(16, 16), 256, 0, stream>>>(
      xb, E_, wihf16, E_, b_f, nullptr, 0, xproj16, 2048, BN_, 2048, E_, nullptr, 0);
  bgemm_kernel<0, false><<<dim3(16, 16), 256, 0, stream>>>(
      xb, E_, wihb16, E_, b_b, nullptr, 0, xproj16 + (size_t)BN_ * 2048, 2048, BN_, 2048, E_, nullptr, 0);
  bgemm_kernel<0, false><<<dim3(16, 16), 256, 0, stream>>>(
      xb, E_, wihd16, E_, b_d, nullptr, 0, xproj16 + (size_t)2 * BN_ * 2048, 2048, BN_, 2048, E_, nullptr, 0);

  // cast2 (runs inside fused kernel, hidden under lstm)
  CastArgs c2;
  {
    const float* s6[6] = {W1, W2, comb_W, vocab_W, Wg_W, ptr_W};
    __hip_bfloat16* d6[6] = {w1_16, w2_16, combw16, vocw16, wgw16, ptrw16};
    int ns[6] = {512 * 512, 512 * 1024, 512 * 1536, 8000 * 512, 512 * 512, 128 * 512};
    int acc = 0;
    for (int k = 0; k < 6; ++k) {
      c2.s[k] = s6[k]; c2.d[k] = (unsigned long long)d6[k]; c2.base[k] = acc;
      acc += ns[k];
    }
    for (int k = 6; k < 12; ++k) { c2.s[k] = nullptr; c2.d[k] = 0; c2.base[k] = 0x7fffffff; }
    c2.total = acc; c2.special = 5;
  }

  hipError_t e1 = hipFuncSetAttribute((const void*)fused_kernel,
                      hipFuncAttributeMaxDynamicSharedMemorySize, 147968);
  (void)e1;
  fused_kernel<<<160, 256, 147968, stream>>>(
      xproj16, Whh_f, Whh_b, Whh_d, hbuf, ehsb, ehsT, catb, c2);

  // dterm = 2 * dec_h @ W1^T (f32) ; etT = 2 * transposed bf16 eterm
  bgemm64_kernel<2, 0><<<dim3(8, 32), 256, 0, stream>>>(
      catb, 1536, w1_16, 512, nullptr, nullptr, dterm, 512, nullptr, nullptr, 0,
      BN_, 512, 512, 0, 0, 0);
  bgemm64_kernel<2, 1><<<dim3(8, 32), 256, 0, stream>>>(
      ehsb, 1024, w2_16, 1024, nullptr, nullptr, nullptr, 0, nullptr, etT, 0,
      BN_, 512, 1024, 0, 0, 0);

  score_kernel<<<16 * 32, 256, 0, stream>>>(dterm, etT, v_att, src_mask, alphab);

  // context = alpha[b] @ ehsT[b]^T -> catb[:,512:1536]
  bgemm64_kernel<0, 0><<<dim3(16, 2, 16), 256, 0, stream>>>(
      alphab, 128, ehsT, 128, nullptr, nullptr, nullptr, 0, nullptr,
      catb + 512, 1536, 128, 1024, 128, 128 * 128, 1024 * 128, 128 * 1536);

  // combined = tanh(cat @ comb_W^T + comb_b) -> bf16
  bgemm64_kernel<1, 0><<<dim3(8, 32), 256, 0, stream>>>(
      catb, 1536, combw16, 1536, comb_b, nullptr, nullptr, 0, nullptr,
      combb, 512, BN_, 512, 1536, 0, 0, 0);

  // vocab logits + confusionset mask
  bgemm_kernel<0, true><<<dim3(63, 16), 256, 0, stream>>>(
      combb, 512, vocw16, 512, vocab_b, out1, V_, nullptr, 0, BN_, V_, 512, cmask, V_);

  // fused wg/base
  bgemm64_kernel<0, 2><<<dim3(10, 32), 256, 0, stream>>>(
      combb, 512, wgw16, 512, Wg_b, ptr_b, wgout, 512, baseb, nullptr, 0,
      BN_, 640, 512, 0, 0, 0);

  pointer_kernel<<<BN_, 256, 0, stream>>>(baseb, wgout, ptr_W, ps_W, ps_b, src_mask, out0);
}

// Round 11
// 586.628 us; speedup vs baseline: 1.2514x; 1.0324x over previous
//
#include <hip/hip_runtime.h>
#include <hip/hip_bf16.h>
#include <math.h>

#define NEGV -1000000000.0f

static constexpr int B_ = 16, N_ = 128, BN_ = 2048;
static constexpr int E_ = 384, V_ = 8000;

typedef __attribute__((ext_vector_type(8))) short short8v;
typedef __attribute__((ext_vector_type(4))) float f32x4;

// ---------------- helpers ----------------
__device__ inline float wave_sum(float v) {
#pragma unroll
  for (int o = 32; o; o >>= 1) v += __shfl_xor(v, o);
  return v;
}
__device__ inline float wave_max(float v) {
#pragma unroll
  for (int o = 32; o; o >>= 1) v = fmaxf(v, __shfl_xor(v, o));
  return v;
}
__device__ inline float fast_tanh(float x) {
  return 1.f - 2.f / (1.f + __expf(2.f * x));
}
__device__ inline float fast_tanh_pre(float x2) {  // input pre-scaled by 2
  return 1.f - 2.f / (1.f + __expf(x2));
}
__device__ inline float fast_sig(float x) {
  return 1.f / (1.f + __expf(-x));
}
__device__ __forceinline__ void gl16(const void* g, void* l) {
  __builtin_amdgcn_global_load_lds((const __attribute__((address_space(1))) void*)g,
                                   (__attribute__((address_space(3))) void*)l, 16, 0, 0);
}

// ---------------- multi-segment fp32 -> bf16 cast ----------------
struct CastArgs {
  const float* s[6];
  unsigned long long d[6];
  int base[6];
  int total;
  int special;  // segment with ptr_W [128][513]->[128][512] packing, or -1
};
__device__ inline void cast_body(const CastArgs& a, int gsize, int gid0) {
  const int nq = a.total >> 2;
  for (int q = gid0; q < nq; q += gsize) {
    const int e = q << 2;
    int k = 5;
    while (e < a.base[k]) --k;
    const int i = e - a.base[k];
    __hip_bfloat16* dst = (__hip_bfloat16*)a.d[k] + i;
    if (k == a.special) {
      const int row = i >> 9, col = i & 511;
      const float* sp = a.s[k] + (size_t)row * 513 + col;
#pragma unroll
      for (int u = 0; u < 4; ++u) dst[u] = __float2bfloat16(sp[u]);
    } else {
      float4 v = *(const float4*)(a.s[k] + i);
      __hip_bfloat16 h0 = __float2bfloat16(v.x), h1 = __float2bfloat16(v.y);
      __hip_bfloat16 h2 = __float2bfloat16(v.z), h3 = __float2bfloat16(v.w);
      ushort4 u4 = {*(unsigned short*)&h0, *(unsigned short*)&h1,
                    *(unsigned short*)&h2, *(unsigned short*)&h3};
      *(ushort4*)dst = u4;
    }
  }
}

// ---------------- prologue: embed + hbuf sentinel-memset + cast1 ----------------
__global__ __launch_bounds__(256) void prologue_kernel(
    const int* __restrict__ ids, const float* __restrict__ emb,
    __hip_bfloat16* __restrict__ xb, __hip_bfloat16* __restrict__ hbuf,
    CastArgs c1) {
  const int bid = blockIdx.x, tid = threadIdx.x;
  if (bid < 256) {
    for (int row = bid; row < 2048; row += 256) {
      const int id = ids[row];
      for (int e = tid; e < E_; e += 256)
        xb[(size_t)row * E_ + e] = __float2bfloat16(emb[(size_t)id * E_ + e]);
    }
  } else if (bid < 288) {
    // sentinel memset via sc0sc1 (write-through: hbuf is only ever read sc0sc1)
    const unsigned total = 3u * 128u * 8192u * 2u;
    const float pf = __builtin_bit_cast(float, 0x7f7f7f7fu);
    f32x4 pat = {pf, pf, pf, pf};
    char* base = (char*)hbuf;
    for (unsigned off = (unsigned)((bid - 256) * 256 + tid) * 16u; off < total;
         off += 32u * 256u * 16u) {
      asm volatile("global_store_dwordx4 %0, %1, %2 sc0 sc1"
                   :: "v"(off), "v"(pat), "s"(base) : "memory");
    }
  } else {
    cast_body(c1, 256 * 256, (bid - 288) * 256 + tid);
  }
}

// ---------------- 128x128-tile bf16 MFMA GEMM body ----------------
template <int ACT, bool MASK>
__device__ __forceinline__ void gemm128_impl(
    const __hip_bfloat16* A, int lda, const __hip_bfloat16* W, int ldw,
    const float* bias, float* C, int ldc, __hip_bfloat16* Cb, int ldcb,
    int N, int K, const int* mask, int ldm, int m0, int n0,
    __hip_bfloat16 (*Al)[4096], __hip_bfloat16 (*Bl)[4096]) {
  const int tid = threadIdx.x;
  const int wid = tid >> 6, lane = tid & 63;
  const int nkt = K >> 5;
  const int rm = (wid >> 1) << 6, rn = (wid & 1) << 6;
  const int lrow = lane & 15, kq = lane >> 4;
  const int fs = ((lrow >> 1) & 3) << 4;

  f32x4 acc[4][4];
#pragma unroll
  for (int i = 0; i < 4; ++i)
#pragma unroll
    for (int j = 0; j < 4; ++j) acc[i][j] = {0.f, 0.f, 0.f, 0.f};

  auto stage = [&](int bi, int kt) {
#pragma unroll
    for (int c = 0; c < 2; ++c) {
      const int p = ((c * 4 + wid) << 6) + lane;
      const int row = p >> 2, cb = (p & 3) << 4;
      const int sw = ((row >> 1) & 3) << 4;
      const unsigned loff = (unsigned)__builtin_amdgcn_readfirstlane((c * 4 + wid) << 10);
      {
        const char* src = (const char*)A + ((size_t)(m0 + row) * lda + (size_t)kt * 32) * 2 + (cb ^ sw);
        gl16(src, (char*)&Al[bi][0] + loff);
      }
      {
        int gr = n0 + row;
        if (gr >= N) gr = N - 1;
        const char* src = (const char*)W + ((size_t)gr * ldw + (size_t)kt * 32) * 2 + (cb ^ sw);
        gl16(src, (char*)&Bl[bi][0] + loff);
      }
    }
  };
  auto compute = [&](int bi) {
    const char* Ab = (const char*)&Al[bi][0];
    const char* Bb = (const char*)&Bl[bi][0];
    const int roff = (kq << 4) ^ fs;
    short8v a[4], b[4];
#pragma unroll
    for (int i = 0; i < 4; ++i)
      a[i] = *(const short8v*)(Ab + (rm + i * 16 + lrow) * 64 + roff);
#pragma unroll
    for (int j = 0; j < 4; ++j)
      b[j] = *(const short8v*)(Bb + (rn + j * 16 + lrow) * 64 + roff);
#pragma unroll
    for (int i = 0; i < 4; ++i)
#pragma unroll
      for (int j = 0; j < 4; ++j)
        acc[i][j] = __builtin_amdgcn_mfma_f32_16x16x32_bf16(a[i], b[j], acc[i][j], 0, 0, 0);
  };

  stage(0, 0);
  for (int kt = 0; kt < nkt; ++kt) {
    __syncthreads();
    if (kt + 1 < nkt) stage((kt + 1) & 1, kt + 1);
    compute(kt & 1);
  }

#pragma unroll
  for (int i = 0; i < 4; ++i) {
#pragma unroll
    for (int r = 0; r < 4; ++r) {
      const int m = m0 + rm + i * 16 + kq * 4 + r;
#pragma unroll
      for (int j = 0; j < 4; ++j) {
        const int n = n0 + rn + j * 16 + lrow;
        if (n < N) {
          float v = acc[i][j][r] + (bias ? bias[n] : 0.f);
          if (ACT == 1) v = fast_tanh(v);
          if (MASK) {
            if (mask[(size_t)m * ldm + n] == 0) v = NEGV;
          }
          if (C) C[(size_t)m * ldc + n] = v;
          if (Cb) Cb[(size_t)m * ldcb + n] = __float2bfloat16(v);
        }
      }
    }
  }
}

// ---------------- 64x64-tile bf16 MFMA GEMM body (runtime act/trout) ----------------
// act: 0 none, 1 tanh(v+bias), 2 v*=2. trout: 0 normal, 1 etT-transposed,
// 2 split wg(tanh,f32 C)/base(raw,f32 C2).
__device__ __forceinline__ void gemm64_impl(
    const __hip_bfloat16* A, int lda, const __hip_bfloat16* W, int ldw,
    const float* bias, const float* bias2,
    float* C, int ldc, float* C2, __hip_bfloat16* Cb, int ldcb,
    int K, int act, int trout, int m0, int n0, char* AlB, char* BlB) {
  const int tid = threadIdx.x;
  const int wid = tid >> 6, lane = tid & 63;
  const int nkt = K >> 5;
  const int rm = (wid >> 1) << 5, rn = (wid & 1) << 5;
  const int lrow = lane & 15, kq = lane >> 4;
  const int fs = ((lrow >> 1) & 3) << 4;

  f32x4 acc[2][2];
#pragma unroll
  for (int i = 0; i < 2; ++i)
#pragma unroll
    for (int j = 0; j < 2; ++j) acc[i][j] = {0.f, 0.f, 0.f, 0.f};

  auto stage = [&](int bi, int kt) {
    const int row = tid >> 2, cb = (tid & 3) << 4;
    const int sw = ((row >> 1) & 3) << 4;
    const unsigned loff = (unsigned)__builtin_amdgcn_readfirstlane(wid << 10);
    {
      const char* src = (const char*)A + ((size_t)(m0 + row) * lda + (size_t)kt * 32) * 2 + (cb ^ sw);
      gl16(src, AlB + bi * 4096 + loff);
    }
    {
      const char* src = (const char*)W + ((size_t)(n0 + row) * ldw + (size_t)kt * 32) * 2 + (cb ^ sw);
      gl16(src, BlB + bi * 4096 + loff);
    }
  };
  auto compute = [&](int bi) {
    const char* Ab = AlB + bi * 4096;
    const char* Bb = BlB + bi * 4096;
    const int roff = (kq << 4) ^ fs;
    short8v a[2], b[2];
#pragma unroll
    for (int i = 0; i < 2; ++i)
      a[i] = *(const short8v*)(Ab + (rm + i * 16 + lrow) * 64 + roff);
#pragma unroll
    for (int j = 0; j < 2; ++j)
      b[j] = *(const short8v*)(Bb + (rn + j * 16 + lrow) * 64 + roff);
#pragma unroll
    for (int i = 0; i < 2; ++i)
#pragma unroll
      for (int j = 0; j < 2; ++j)
        acc[i][j] = __builtin_amdgcn_mfma_f32_16x16x32_bf16(a[i], b[j], acc[i][j], 0, 0, 0);
  };

  stage(0, 0);
  for (int kt = 0; kt < nkt; ++kt) {
    __syncthreads();
    if (kt + 1 < nkt) stage((kt + 1) & 1, kt + 1);
    compute(kt & 1);
  }

#pragma unroll
  for (int i = 0; i < 2; ++i) {
#pragma unroll
    for (int r = 0; r < 4; ++r) {
      const int m = m0 + rm + i * 16 + kq * 4 + r;
#pragma unroll
      for (int j = 0; j < 2; ++j) {
        const int n = n0 + rn + j * 16 + lrow;
        float v = acc[i][j][r];
        if (trout == 2) {
          if (n < 512) {
            C[(size_t)m * ldc + n] = fast_tanh(v + bias[n]);
          } else {
            C2[(size_t)m * 128 + (n - 512)] = v + bias2[n - 512];
          }
        } else {
          if (act == 2) v *= 2.f;
          else {
            v += (bias ? bias[n] : 0.f);
            if (act == 1) v = fast_tanh(v);
          }
          if (trout == 1) {
            Cb[(((size_t)(m >> 7) * 512 + n) << 7) + (m & 127)] = __float2bfloat16(v);
          } else {
            if (C) C[(size_t)m * ldc + n] = v;
            if (Cb) Cb[(size_t)m * ldcb + n] = __float2bfloat16(v);
          }
        }
      }
    }
  }
}

// ---------------- xproj: z-batched 128-tile GEMM ----------------
__global__ __launch_bounds__(256) void xproj_kernel(
    const __hip_bfloat16* __restrict__ A, const __hip_bfloat16* __restrict__ Wih,
    const float* __restrict__ b0, const float* __restrict__ b1,
    const float* __restrict__ b2, __hip_bfloat16* __restrict__ xproj16) {
  __shared__ __hip_bfloat16 Al[2][4096], Bl[2][4096];
  const int z = blockIdx.z;
  const float* bias = (z == 0) ? b0 : (z == 1 ? b1 : b2);
  gemm128_impl<0, false>(A, E_, Wih + (size_t)z * 2048 * 384, E_, bias,
                         nullptr, 0, xproj16 + (size_t)z * BN_ * 2048, 2048,
                         2048, E_, nullptr, 0, blockIdx.y * 128,
                         blockIdx.x * 128, Al, Bl);
}

// ---------------- qk: dterm + etT merged ----------------
__global__ __launch_bounds__(256) void qk_kernel(
    const __hip_bfloat16* __restrict__ catb, const __hip_bfloat16* __restrict__ ehsb,
    const __hip_bfloat16* __restrict__ w1, const __hip_bfloat16* __restrict__ w2,
    float* __restrict__ dterm, __hip_bfloat16* __restrict__ etT) {
  __shared__ char AlB[8192], BlB[8192];
  const int bid = blockIdx.x;
  if (bid < 256) {
    const int bx = bid & 7, by = bid >> 3;
    gemm64_impl(catb, 1536, w1, 512, nullptr, nullptr, dterm, 512, nullptr,
                nullptr, 0, 512, 2, 0, by * 64, bx * 64, AlB, BlB);
  } else {
    const int l = bid - 256;
    const int bx = l & 7, by = l >> 3;
    gemm64_impl(ehsb, 1024, w2, 1024, nullptr, nullptr, nullptr, 0, nullptr,
                etT, 0, 1024, 2, 1, by * 64, bx * 64, AlB, BlB);
  }
}

// ---------------- context: batched 64-tile GEMM ----------------
__global__ __launch_bounds__(256) void ctx_kernel(
    const __hip_bfloat16* __restrict__ alphab, const __hip_bfloat16* __restrict__ ehsT,
    __hip_bfloat16* __restrict__ catbCtx) {
  __shared__ char AlB[8192], BlB[8192];
  const int z = blockIdx.z;
  gemm64_impl(alphab + (size_t)z * 128 * 128, 128,
              ehsT + (size_t)z * 1024 * 128, 128, nullptr, nullptr, nullptr, 0,
              nullptr, catbCtx + (size_t)z * 128 * 1536, 1536, 128, 0, 0,
              blockIdx.y * 64, blockIdx.x * 64, AlB, BlB);
}

// ---------------- comb ----------------
__global__ __launch_bounds__(256) void comb_kernel(
    const __hip_bfloat16* __restrict__ catb, const __hip_bfloat16* __restrict__ combw,
    const float* __restrict__ comb_b, __hip_bfloat16* __restrict__ combb) {
  __shared__ char AlB[8192], BlB[8192];
  gemm64_impl(catb, 1536, combw, 1536, comb_b, nullptr, nullptr, 0, nullptr,
              combb, 512, 1536, 1, 0, blockIdx.y * 64, blockIdx.x * 64, AlB, BlB);
}

// ---------------- tail: vocab (128-tile) + wg/base (64-tile) merged ----------------
__global__ __launch_bounds__(256) void tail_kernel(
    const __hip_bfloat16* __restrict__ combb, const __hip_bfloat16* __restrict__ vocw,
    const float* __restrict__ vocab_b, float* __restrict__ out1,
    const int* __restrict__ cmask,
    const __hip_bfloat16* __restrict__ wgw, const float* __restrict__ Wg_b,
    const float* __restrict__ ptr_b, float* __restrict__ wgout,
    float* __restrict__ baseb) {
  __shared__ __hip_bfloat16 Al[2][4096], Bl[2][4096];
  const int bid = blockIdx.x;
  if (bid < 1008) {
    const int bx = bid % 63, by = bid / 63;
    gemm128_impl<0, true>(combb, 512, vocw, 512, vocab_b, out1, V_, nullptr, 0,
                          V_, 512, cmask, V_, by * 128, bx * 128, Al, Bl);
  } else {
    const int l = bid - 1008;
    const int bx = l % 10, by = l / 10;
    gemm64_impl(combb, 512, wgw, 512, Wg_b, ptr_b, wgout, 512, baseb, nullptr,
                0, 512, 0, 2, by * 64, bx * 64, (char*)Al, (char*)Bl);
  }
}

// ---------------- FUSED: lstm (96 blocks) + cast2 (64 blocks) ----------------
__global__ __launch_bounds__(256) void fused_kernel(
    const __hip_bfloat16* __restrict__ xp16,   // [3][2048][2048]
    const float* __restrict__ whhF, const float* __restrict__ whhB,
    const float* __restrict__ whhD,
    __hip_bfloat16* __restrict__ hbuf,         // [3][128][32][16b][16d]
    __hip_bfloat16* __restrict__ ehsb, __hip_bfloat16* __restrict__ ehsT,
    __hip_bfloat16* __restrict__ catb,
    CastArgs ca2) {
  extern __shared__ char sm[];
  const int bid = blockIdx.x;
  const int tid = threadIdx.x;

  if (bid >= 96) {  // ---- cast2 role (plain reads, no polling) ----
    cast_body(ca2, 64 * 256, (bid - 96) * 256 + tid);
    return;
  }

  // ---- LSTM role ----
  const int l = bid >> 5, g = bid & 31;
  const int lane = tid & 63, wid = tid >> 6;
  char* smW = sm;                                   // 65536
  char* smH = sm + 65536;                           // 16384
  __hip_bfloat16* hout = (__hip_bfloat16*)(sm + 65536 + 16384);  // 512
  char* hist = sm + 65536 + 16384 + 512;            // 65536: [s][b][d] ushort

  const float* wsrc = (l == 0) ? whhF : ((l == 1) ? whhB : whhD);
  auto cv = [](float x) -> unsigned {
    __hip_bfloat16 h = __float2bfloat16(x);
    return (unsigned)*(unsigned short*)&h;
  };
  for (int p = tid; p < 4096; p += 256) {
    const int r = p >> 6, cb = (p & 63) << 4;
    const int grow = (r & 3) * 512 + (g << 4) + (r >> 2);
    const float* srcp = wsrc + (size_t)grow * 512 + ((p & 63) << 3);
    float4 u0 = *(const float4*)srcp;
    float4 u1 = *(const float4*)(srcp + 4);
    uint4 q;
    q.x = cv(u0.x) | (cv(u0.y) << 16);
    q.y = cv(u0.z) | (cv(u0.w) << 16);
    q.z = cv(u1.x) | (cv(u1.y) << 16);
    q.w = cv(u1.z) | (cv(u1.w) << 16);
    *(uint4*)(smW + r * 1024 + (cb ^ ((r & 7) << 4))) = q;
  }

  const int lrow = lane & 15, kq = lane >> 4;
  const int swz = (lrow & 7) << 4;
  const char* aB = smW + (wid * 16 + lrow) * 1024;
  const char* bB = smH + lrow * 1024;
  const int dl16 = wid * 4 + kq;
  const int dg = (g << 4) + dl16;
  const int bb = lrow;
  const bool rev = (l == 1);
  const __hip_bfloat16* xl = xp16 + (size_t)l * 2048 * 2048;
  __hip_bfloat16* hb_l = hbuf + (size_t)l * 128 * 8192;
  const int gq = tid >> 3;
  const int b0 = (tid & 7) * 2;
  const int gb = gq * 32;
  const int sw0 = (b0 & 7) << 4, sw1 = ((b0 + 1) & 7) << 4;
  float c = 0.f;

  for (int s = 0; s < 128; ++s) {
    const int t = rev ? 127 - s : s;
    const size_t xro = (size_t)(bb * 128 + t) * 2048 + dg;
    const float xgi = __bfloat162float(xl[xro]);
    const float xgf = __bfloat162float(xl[xro + 512]);
    const float xgg = __bfloat162float(xl[xro + 1024]);
    const float xgo = __bfloat162float(xl[xro + 1536]);

    if (s > 0) {
      if (gq != g) {
        const char* hsrc = (const char*)(hb_l + (size_t)(s - 1) * 8192);
        const unsigned loff = (unsigned)(tid * 64);
        unsigned hv;
        while (true) {
          asm volatile(
              "global_load_ushort %0, %1, %2 sc0 sc1\n\t"
              "s_waitcnt vmcnt(0)"
              : "=&v"(hv) : "v"(loff), "s"(hsrc) : "memory");
          if ((hv & 0xffffu) != 0x7f7fu) break;
          __builtin_amdgcn_s_sleep(1);
        }
        f32x4 q0, q1, q2, q3;
        asm volatile(
            "global_load_dwordx4 %0, %4, %5 sc0 sc1\n\t"
            "global_load_dwordx4 %1, %4, %5 offset:16 sc0 sc1\n\t"
            "global_load_dwordx4 %2, %4, %5 offset:32 sc0 sc1\n\t"
            "global_load_dwordx4 %3, %4, %5 offset:48 sc0 sc1\n\t"
            "s_waitcnt vmcnt(0)"
            : "=&v"(q0), "=&v"(q1), "=&v"(q2), "=&v"(q3)
            : "v"(loff), "s"(hsrc) : "memory");
        *(f32x4*)(smH + b0 * 1024 + (gb ^ sw0)) = q0;
        *(f32x4*)(smH + b0 * 1024 + ((gb + 16) ^ sw0)) = q1;
        *(f32x4*)(smH + (b0 + 1) * 1024 + (gb ^ sw1)) = q2;
        *(f32x4*)(smH + (b0 + 1) * 1024 + ((gb + 16) ^ sw1)) = q3;
      } else {
        const char* hl = (const char*)hout + b0 * 32;
        f32x4 c0 = *(const f32x4*)(hl);
        f32x4 c1 = *(const f32x4*)(hl + 16);
        f32x4 c2 = *(const f32x4*)(hl + 32);
        f32x4 c3 = *(const f32x4*)(hl + 48);
        *(f32x4*)(smH + b0 * 1024 + (gb ^ sw0)) = c0;
        *(f32x4*)(smH + b0 * 1024 + ((gb + 16) ^ sw0)) = c1;
        *(f32x4*)(smH + (b0 + 1) * 1024 + (gb ^ sw1)) = c2;
        *(f32x4*)(smH + (b0 + 1) * 1024 + ((gb + 16) ^ sw1)) = c3;
      }
    } else {
      const f32x4 z = {0.f, 0.f, 0.f, 0.f};
      *(f32x4*)(smH + b0 * 1024 + (gb ^ sw0)) = z;
      *(f32x4*)(smH + b0 * 1024 + ((gb + 16) ^ sw0)) = z;
      *(f32x4*)(smH + (b0 + 1) * 1024 + (gb ^ sw1)) = z;
      *(f32x4*)(smH + (b0 + 1) * 1024 + ((gb + 16) ^ sw1)) = z;
    }
    __syncthreads();  // A: smH fully staged

    f32x4 acc0 = {0.f, 0.f, 0.f, 0.f}, acc1 = {0.f, 0.f, 0.f, 0.f};
#pragma unroll
    for (int kt = 0; kt < 16; kt += 2) {
      const int off0 = ((kt * 64 + (kq << 4)) ^ swz);
      const int off1 = (((kt + 1) * 64 + (kq << 4)) ^ swz);
      short8v a0 = *(const short8v*)(aB + off0);
      short8v b0v = *(const short8v*)(bB + off0);
      short8v a1 = *(const short8v*)(aB + off1);
      short8v b1v = *(const short8v*)(bB + off1);
      acc0 = __builtin_amdgcn_mfma_f32_16x16x32_bf16(a0, b0v, acc0, 0, 0, 0);
      acc1 = __builtin_amdgcn_mfma_f32_16x16x32_bf16(a1, b1v, acc1, 0, 0, 0);
    }
    const f32x4 acc = acc0 + acc1;  // acc[r] = gate r for (dg, bb)

    const float gi = acc[0] + xgi;
    const float gf = acc[1] + xgf;
    const float gg = acc[2] + xgg;
    const float go = acc[3] + xgo;
    c = fmaf(fast_sig(gf), c, fast_sig(gi) * fast_tanh(gg));
    const float h = fast_sig(go) * fast_tanh(c);
    __hip_bfloat16 hb16 = __float2bfloat16(h);
    const unsigned short hraw = *(unsigned short*)&hb16;
    hout[bb * 16 + dl16] = hb16;
    *(unsigned short*)(hist + s * 512 + (bb * 16 + dl16) * 2) = hraw;
    __syncthreads();  // B: MFMA reads done + hout complete

    if (s < 127 && wid == (s & 3) && (lane < 32)) {
      f32x4 hv4 = *(const f32x4*)((const char*)hout + lane * 16);
      char* hdst = (char*)(hb_l + (size_t)s * 8192);
      asm volatile("global_store_dwordx4 %0, %1, %2 sc0 sc1"
                   :: "v"((unsigned)((g << 9) + lane * 16)), "v"(hv4), "s"(hdst)
                   : "memory");
    }
  }

  // ---- epilogue: write own slice of ehsb/ehsT/catb from LDS history ----
  __syncthreads();
  const int bb2 = tid >> 4, lo2 = tid & 15;
  if (l < 2) {
    const int hoff = (bb2 * 16 + lo2) * 2;
    char* dstT = (char*)(ehsT + ((size_t)bb2 * 1024 + l * 512 + (g << 4) + lo2) * 128);
    for (int tc = 0; tc < 128; tc += 32) {
      unsigned v[16];
#pragma unroll
      for (int w = 0; w < 16; ++w) {
        const int t0 = tc + 2 * w;
        const int s0 = rev ? 127 - t0 : t0;
        const int s1 = rev ? 126 - t0 : t0 + 1;
        unsigned a = *(const unsigned short*)(hist + s0 * 512 + hoff);
        unsigned b2 = *(const unsigned short*)(hist + s1 * 512 + hoff);
        v[w] = a | (b2 << 16);
      }
#pragma unroll
      for (int q = 0; q < 4; ++q)
        *(uint4*)(dstT + tc * 2 + q * 16) =
            make_uint4(v[q * 4], v[q * 4 + 1], v[q * 4 + 2], v[q * 4 + 3]);
    }
    for (int k = 0; k < 8; ++k) {
      const int t = lo2 * 8 + k;
      const int s0 = rev ? 127 - t : t;
      const char* srcp = hist + s0 * 512 + bb2 * 32;
      uint4 ra = *(const uint4*)srcp;
      uint4 rb = *(const uint4*)(srcp + 16);
      char* dp = (char*)(ehsb + ((size_t)(bb2 * 128 + t)) * 1024 + l * 512 + (g << 4));
      *(uint4*)dp = ra;
      *(uint4*)(dp + 16) = rb;
    }
  } else {
    for (int k = 0; k < 8; ++k) {
      const int t = lo2 * 8 + k;
      const char* srcp = hist + t * 512 + bb2 * 32;
      uint4 ra = *(const uint4*)srcp;
      uint4 rb = *(const uint4*)(srcp + 16);
      char* dp = (char*)(catb + ((size_t)(bb2 * 128 + t)) * 1536 + (g << 4));
      *(uint4*)dp = ra;
      *(uint4*)(dp + 16) = rb;
    }
  }
}

// ---------------- score + softmax -> alpha; 4 t's per block ----------------
__global__ __launch_bounds__(256) void score_kernel(
    const float* __restrict__ dterm, const __hip_bfloat16* __restrict__ etT,
    const float* __restrict__ v_att, const int* __restrict__ src_mask,
    __hip_bfloat16* __restrict__ alphab) {
  const int b = blockIdx.x >> 5, tg = blockIdx.x & 31;
  const int t0 = tg * 4;
  const int tid = threadIdx.x;
  __shared__ float dt[4][512], vs[512], red[4][4][128], al[4][128];
  for (int i = tid; i < 2048; i += 256)
    dt[i >> 9][i & 511] = dterm[((size_t)(b * 128 + t0 + (i >> 9))) * 512 + (i & 511)];
  vs[tid] = v_att[tid];
  vs[tid + 256] = v_att[256 + tid];
  __syncthreads();
  const int n0 = (tid & 63) << 1, ah = tid >> 6;
  {
    const __hip_bfloat16* ep = etT + (((size_t)b * 512 + ah * 128) << 7) + n0;
    const float* vp = vs + ah * 128;
    const float* dp0 = &dt[0][ah * 128];
    const float* dp1 = &dt[1][ah * 128];
    const float* dp2 = &dt[2][ah * 128];
    const float* dp3 = &dt[3][ah * 128];
    float p00 = 0, p01 = 0, p10 = 0, p11 = 0, p20 = 0, p21 = 0, p30 = 0, p31 = 0;
    for (int a = 0; a < 128; ++a) {
      const unsigned u = *(const unsigned*)(ep + ((size_t)a << 7));
      unsigned u0 = u << 16, u1 = u & 0xffff0000u;
      const float e0 = __builtin_bit_cast(float, u0);
      const float e1 = __builtin_bit_cast(float, u1);
      const float va = vp[a];
      p00 = fmaf(va, fast_tanh_pre(dp0[a] + e0), p00);
      p01 = fmaf(va, fast_tanh_pre(dp0[a] + e1), p01);
      p10 = fmaf(va, fast_tanh_pre(dp1[a] + e0), p10);
      p11 = fmaf(va, fast_tanh_pre(dp1[a] + e1), p11);
      p20 = fmaf(va, fast_tanh_pre(dp2[a] + e0), p20);
      p21 = fmaf(va, fast_tanh_pre(dp2[a] + e1), p21);
      p30 = fmaf(va, fast_tanh_pre(dp3[a] + e0), p30);
      p31 = fmaf(va, fast_tanh_pre(dp3[a] + e1), p31);
    }
    red[0][ah][n0] = p00; red[0][ah][n0 + 1] = p01;
    red[1][ah][n0] = p10; red[1][ah][n0 + 1] = p11;
    red[2][ah][n0] = p20; red[2][ah][n0 + 1] = p21;
    red[3][ah][n0] = p30; red[3][ah][n0 + 1] = p31;
  }
  __syncthreads();
#pragma unroll
  for (int tp = 0; tp < 2; ++tp) {
    const int tt = tp * 2 + (tid >> 7);
    const int n = tid & 127;
    float sc = red[tt][0][n] + red[tt][1][n] + red[tt][2][n] + red[tt][3][n];
    if (src_mask[b * 128 + n] == 0) sc = NEGV;
    al[tt][n] = sc;
  }
  __syncthreads();
  {
    const int tt = tid >> 6, lane = tid & 63;
    const float v0 = al[tt][lane], v1 = al[tt][lane + 64];
    const float m = wave_max(fmaxf(v0, v1));
    const float e0 = __expf(v0 - m), e1 = __expf(v1 - m);
    const float inv = 1.f / wave_sum(e0 + e1);
    __hip_bfloat16* ap = alphab + ((size_t)(b * 128 + t0 + tt)) * 128;
    ap[lane] = __float2bfloat16(e0 * inv);
    ap[lane + 64] = __float2bfloat16(e1 * inv);
  }
}

// ---------------- pointer head assembly ----------------
__global__ __launch_bounds__(256) void pointer_kernel(
    const float* __restrict__ base, const float* __restrict__ wgout,
    const float* __restrict__ ptr_W, const float* __restrict__ ps_W,
    const float* __restrict__ ps_b, const int* __restrict__ src_mask,
    float* __restrict__ out0) {
  const int bt = blockIdx.x;
  const int b = bt >> 7, t = bt & 127;
  const int tid = threadIdx.x;
  __shared__ float r0[4], r1[4], r2[4], fin[3];
  float off_p = 0.f, diag_p = 0.f, sent_p;
  if (tid < 128) {
    const float ba = base[(size_t)bt * 128 + tid];
    const float pw = ps_W[tid];
    off_p = tanhf(ba) * pw;
    diag_p = tanhf(ba + ptr_W[tid * 513 + 512]) * pw;
  }
  sent_p = wgout[(size_t)bt * 512 + tid] + wgout[(size_t)bt * 512 + 256 + tid];
  off_p = wave_sum(off_p);
  diag_p = wave_sum(diag_p);
  sent_p = wave_sum(sent_p);
  const int wid = tid >> 6, lane = tid & 63;
  if (lane == 0) { r0[wid] = off_p; r1[wid] = diag_p; r2[wid] = sent_p; }
  __syncthreads();
  if (tid == 0) {
    const float psb = ps_b[0];
    fin[0] = r0[0] + r0[1] + r0[2] + r0[3] + psb;
    fin[1] = r1[0] + r1[1] + r1[2] + r1[3] + psb;
    fin[2] = r2[0] + r2[1] + r2[2] + r2[3];
  }
  __syncthreads();
  const float s_off = fin[0], s_diag = fin[1], sent = fin[2];
  if (tid < 129) {
    float v;
    if (tid == 128) v = sent;
    else {
      v = (tid == t) ? s_diag : s_off;
      if (src_mask[b * 128 + tid] == 0) v = NEGV;
    }
    out0[(size_t)bt * 129 + tid] = v;
  }
}

// ---------------- launch ----------------
extern "C" void kernel_launch(void* const* d_in, const int* in_sizes, int n_in,
                              void* d_out, int out_size, void* d_ws, size_t ws_size,
                              hipStream_t stream) {
  const int* src_ids   = (const int*)d_in[0];
  const int* src_mask  = (const int*)d_in[1];
  const int* cmask     = (const int*)d_in[2];
  const float* emb     = (const float*)d_in[3];
  const float* Wih_f   = (const float*)d_in[4];
  const float* Whh_f   = (const float*)d_in[5];
  const float* b_f     = (const float*)d_in[6];
  const float* Wih_b   = (const float*)d_in[7];
  const float* Whh_b   = (const float*)d_in[8];
  const float* b_b     = (const float*)d_in[9];
  const float* Wih_d   = (const float*)d_in[10];
  const float* Whh_d   = (const float*)d_in[11];
  const float* b_d     = (const float*)d_in[12];
  const float* W1      = (const float*)d_in[13];
  const float* W2      = (const float*)d_in[14];
  const float* v_att   = (const float*)d_in[15];
  const float* comb_W  = (const float*)d_in[16];
  const float* comb_b  = (const float*)d_in[17];
  const float* vocab_W = (const float*)d_in[18];
  const float* vocab_b = (const float*)d_in[19];
  const float* Wg_W    = (const float*)d_in[20];
  const float* Wg_b    = (const float*)d_in[21];
  const float* ptr_W   = (const float*)d_in[22];
  const float* ptr_b   = (const float*)d_in[23];
  const float* ps_W    = (const float*)d_in[24];
  const float* ps_b    = (const float*)d_in[25];
  (void)in_sizes; (void)n_in; (void)out_size; (void)ws_size;

  char* wsb = (char*)d_ws;
  size_t o = 0;
  auto alloc = [&](size_t bytes) { char* p = wsb + o; o = (o + bytes + 255) & ~(size_t)255; return p; };
  __hip_bfloat16* xb      = (__hip_bfloat16*)alloc((size_t)BN_ * E_ * 2);
  __hip_bfloat16* xproj16 = (__hip_bfloat16*)alloc((size_t)3 * BN_ * 2048 * 2);
  __hip_bfloat16* ehsb    = (__hip_bfloat16*)alloc((size_t)BN_ * 1024 * 2);
  __hip_bfloat16* ehsT    = (__hip_bfloat16*)alloc((size_t)16 * 1024 * 128 * 2);
  __hip_bfloat16* catb    = (__hip_bfloat16*)alloc((size_t)BN_ * 1536 * 2);
  float* dterm            = (float*)alloc((size_t)BN_ * 512 * 4);
  __hip_bfloat16* etT     = (__hip_bfloat16*)alloc((size_t)16 * 512 * 128 * 2);
  __hip_bfloat16* alphab  = (__hip_bfloat16*)alloc((size_t)BN_ * 128 * 2);
  __hip_bfloat16* combb   = (__hip_bfloat16*)alloc((size_t)BN_ * 512 * 2);
  float* wgout            = (float*)alloc((size_t)BN_ * 512 * 4);
  float* baseb            = (float*)alloc((size_t)BN_ * 128 * 4);
  __hip_bfloat16* hbuf    = (__hip_bfloat16*)alloc((size_t)3 * 128 * 8192 * 2);
  __hip_bfloat16* wih16   = (__hip_bfloat16*)alloc((size_t)3 * 2048 * 384 * 2);
  __hip_bfloat16* w1_16   = (__hip_bfloat16*)alloc((size_t)512 * 512 * 2);
  __hip_bfloat16* w2_16   = (__hip_bfloat16*)alloc((size_t)512 * 1024 * 2);
  __hip_bfloat16* combw16 = (__hip_bfloat16*)alloc((size_t)512 * 1536 * 2);
  __hip_bfloat16* vocw16  = (__hip_bfloat16*)alloc((size_t)8000 * 512 * 2);
  __hip_bfloat16* wgw16   = (__hip_bfloat16*)alloc((size_t)512 * 512 * 2);
  __hip_bfloat16* ptrw16  = (__hip_bfloat16*)alloc((size_t)128 * 512 * 2);

  float* out0 = (float*)d_out;
  float* out1 = out0 + (size_t)BN_ * 129;

  // cast1: the three Wih -> one contiguous wih16 buffer
  CastArgs c1;
  {
    const float* s3[3] = {Wih_f, Wih_b, Wih_d};
    int acc = 0;
    for (int k = 0; k < 3; ++k) {
      c1.s[k] = s3[k];
      c1.d[k] = (unsigned long long)(wih16 + (size_t)k * 2048 * 384);
      c1.base[k] = acc;
      acc += 2048 * 384;
    }
    for (int k = 3; k < 6; ++k) { c1.s[k] = nullptr; c1.d[k] = 0; c1.base[k] = 0x7fffffff; }
    c1.total = acc; c1.special = -1;
  }
  // cast2 (runs inside fused kernel, hidden under lstm)
  CastArgs c2;
  {
    const float* s6[6] = {W1, W2, comb_W, vocab_W, Wg_W, ptr_W};
    __hip_bfloat16* d6[6] = {w1_16, w2_16, combw16, vocw16, wgw16, ptrw16};
    int ns[6] = {512 * 512, 512 * 1024, 512 * 1536, 8000 * 512, 512 * 512, 128 * 512};
    int acc = 0;
    for (int k = 0; k < 6; ++k) {
      c2.s[k] = s6[k]; c2.d[k] = (unsigned long long)d6[k]; c2.base[k] = acc;
      acc += ns[k];
    }
    c2.total = acc; c2.special = 5;
  }

  // 1) prologue: embed + hbuf sentinel memset (sc0sc1) + cast1
  prologue_kernel<<<544, 256, 0, stream>>>(src_ids, emb, xb, hbuf, c1);

  // 2) xproj batched over z (bias folded), bf16 out
  xproj_kernel<<<dim3(16, 16, 3), 256, 0, stream>>>(
      xb, wih16, b_f, b_b, b_d, xproj16);

  // 3) fused lstm + cast2
  hipError_t e1 = hipFuncSetAttribute((const void*)fused_kernel,
                      hipFuncAttributeMaxDynamicSharedMemorySize, 147968);
  (void)e1;
  fused_kernel<<<160, 256, 147968, stream>>>(
      xproj16, Whh_f, Whh_b, Whh_d, hbuf, ehsb, ehsT, catb, c2);

  // 4) dterm (x2) + etT (x2, transposed) merged
  qk_kernel<<<512, 256, 0, stream>>>(catb, ehsb, w1_16, w2_16, dterm, etT);

  // 5) score + softmax
  score_kernel<<<16 * 32, 256, 0, stream>>>(dterm, etT, v_att, src_mask, alphab);

  // 6) context = alpha[b] @ ehsT[b]^T -> catb[:,512:1536]
  ctx_kernel<<<dim3(16, 2, 16), 256, 0, stream>>>(alphab, ehsT, catb + 512);

  // 7) combined = tanh(cat @ comb_W^T + comb_b) -> bf16
  comb_kernel<<<dim3(8, 32), 256, 0, stream>>>(catb, combw16, comb_b, combb);

  // 8) vocab (+mask) and wg/base merged
  tail_kernel<<<1328, 256, 0, stream>>>(combb, vocw16, vocab_b, out1, cmask,
                                        wgw16, Wg_b, ptr_b, wgout, baseb);

  // 9) pointer head
  pointer_kernel<<<BN_, 256, 0, stream>>>(baseb, wgout, ptr_W, ps_W, ps_b, src_mask, out0);
}